// Round 1
// baseline (1642.275 us; speedup 1.0000x reference)
//
#include <hip/hip_runtime.h>
#include <math.h>

#define BB 128
#define LL 720
#define CC 321
#define HH 128
#define PP 336
#define MM 512

// ---------------------------------------------------------------------------
// Kernel 1: effective (smeared) weights.
//   trend[b,l,c] = (1/25) * sum_{k=0..24} x[b, clamp(l+k-12), c]
//   => sum_l trend[l]*W[h,l] = sum_j x[j]*smear(W)[h,j]
//   smear(W)[h,j] = (1/25) * { interior: sum_{l=j-12..j+12 clipped} W[h,l]
//                              j==0:    sum_{l=0..12} (13-l) W[h,l]
//                              j==L-1:  sum_{d=0..12} (13-d) W[h,L-1-d] }
//   BsEff[j,h] = Ws1[h,j] - smear(Ws1)[h,j]   (seasonal branch: x - trend)
//   BtEff[j,h] = smear(Wt1)[h,j]              (trend branch)
// ---------------------------------------------------------------------------
__global__ void weff_kernel(const float* __restrict__ Ws1,
                            const float* __restrict__ Wt1,
                            float* __restrict__ BsEff,
                            float* __restrict__ BtEff) {
  int idx = blockIdx.x * 256 + threadIdx.x;
  if (idx >= LL * HH) return;
  int h = idx % HH, j = idx / HH;
  float ss = 0.f, st = 0.f;
  if (j == 0) {
    for (int l = 0; l <= 12; ++l) {
      float w = 13.f - (float)l;
      ss += w * Ws1[h * LL + l];
      st += w * Wt1[h * LL + l];
    }
  } else if (j == LL - 1) {
    for (int d = 0; d <= 12; ++d) {
      float w = 13.f - (float)d;
      ss += w * Ws1[h * LL + LL - 1 - d];
      st += w * Wt1[h * LL + LL - 1 - d];
    }
  } else {
    int lo = j - 12 < 0 ? 0 : j - 12;
    int hi = j + 12 > LL - 1 ? LL - 1 : j + 12;
    for (int l = lo; l <= hi; ++l) {
      ss += Ws1[h * LL + l];
      st += Wt1[h * LL + l];
    }
  }
  ss *= (1.f / 25.f);
  st *= (1.f / 25.f);
  BsEff[idx] = Ws1[h * LL + j] - ss;
  BtEff[idx] = st;
}

// ---------------------------------------------------------------------------
// Kernel 2: fused dual-branch GEMM1 + sigmoid.
//   For batch b: out_s[c,h] = sigmoid(sum_l x[l,c]*BsEff[l,h] + bs1[h])
//                out_t[c,h] = sigmoid(sum_l x[l,c]*BtEff[l,h] + bt1[h])
//   Written into r2s/r2t[:, 128..255] (the "repres" half of the concat).
//   Tile 64(c) x 64(h), 256 threads, 4x4 per thread, K-chunk 16.
// ---------------------------------------------------------------------------
__global__ __launch_bounds__(256) void gemm1_kernel(
    const float* __restrict__ x,
    const float* __restrict__ BsEff, const float* __restrict__ BtEff,
    const float* __restrict__ bs1, const float* __restrict__ bt1,
    float* __restrict__ r2s, float* __restrict__ r2t) {
  int b = blockIdx.z;
  int c0 = blockIdx.x * 64;
  int h0 = blockIdx.y * 64;
  __shared__ float xs[16][64];
  __shared__ float ws[16][64];
  __shared__ float wt[16][64];
  int tid = threadIdx.x;
  int tx = tid & 15, ty = tid >> 4;
  float accS[4][4] = {{0.f}}, accT[4][4] = {{0.f}};
  const float* xb = x + (size_t)b * LL * CC;

  for (int l0 = 0; l0 < LL; l0 += 16) {
#pragma unroll
    for (int i = 0; i < 4; ++i) {
      int e = tid + i * 256;
      int kl = e >> 6, q = e & 63;
      int c = c0 + q;
      xs[kl][q] = (c < CC) ? xb[(size_t)(l0 + kl) * CC + c] : 0.f;
      ws[kl][q] = BsEff[(l0 + kl) * HH + h0 + q];
      wt[kl][q] = BtEff[(l0 + kl) * HH + h0 + q];
    }
    __syncthreads();
#pragma unroll
    for (int kl = 0; kl < 16; ++kl) {
      float4 a4 = *(const float4*)&xs[kl][tx * 4];
      float4 s4 = *(const float4*)&ws[kl][ty * 4];
      float4 t4 = *(const float4*)&wt[kl][ty * 4];
      float a[4] = {a4.x, a4.y, a4.z, a4.w};
      float bsv[4] = {s4.x, s4.y, s4.z, s4.w};
      float btv[4] = {t4.x, t4.y, t4.z, t4.w};
#pragma unroll
      for (int i = 0; i < 4; ++i)
#pragma unroll
        for (int j = 0; j < 4; ++j) {
          accS[i][j] = fmaf(a[i], bsv[j], accS[i][j]);
          accT[i][j] = fmaf(a[i], btv[j], accT[i][j]);
        }
    }
    __syncthreads();
  }

#pragma unroll
  for (int i = 0; i < 4; ++i) {
    int c = c0 + tx * 4 + i;
    if (c >= CC) continue;
    size_t n = (size_t)b * CC + c;
    float4 vs, vt;
    float* pvs = &vs.x;
    float* pvt = &vt.x;
#pragma unroll
    for (int j = 0; j < 4; ++j) {
      int h = h0 + ty * 4 + j;
      float es = accS[i][j] + bs1[h];
      float et = accT[i][j] + bt1[h];
      pvs[j] = 1.f / (1.f + __expf(-es));
      pvt[j] = 1.f / (1.f + __expf(-et));
    }
    *(float4*)&r2s[n * 256 + 128 + h0 + ty * 4] = vs;
    *(float4*)&r2t[n * 256 + 128 + h0 + ty * 4] = vt;
  }
}

// ---------------------------------------------------------------------------
// Kernel 3: fused memory-enhance (scores -> softmax -> PV), one branch.
//   16 rows per block, 256 threads. mem staged 64 rows at a time in LDS.
//   reads r from r2[:,128..255], writes attention@mem into r2[:,0..127].
// ---------------------------------------------------------------------------
__global__ __launch_bounds__(256) void memenh_kernel(
    const float* __restrict__ mem, float* __restrict__ r2) {
  int n0 = blockIdx.x * 16;
  __shared__ float rloc[16][132];
  __shared__ float sc[16][516];
  __shared__ float memt[64][132];
  __shared__ float red[16][17];
  int tid = threadIdx.x;

  // stage the 16 r-rows (float4)
#pragma unroll
  for (int i = 0; i < 2; ++i) {
    int e = tid + i * 256;          // 0..511 float4s
    int r = e >> 5, d4 = (e & 31) * 4;
    float4 v = *(const float4*)&r2[(size_t)(n0 + r) * 256 + 128 + d4];
    *(float4*)&rloc[r][d4] = v;
  }
  __syncthreads();

  // ---- scores: sc[r][f] = dot(rloc[r], mem[f]) ----
  int rb = (tid >> 6) * 4;   // wave -> 4 rows
  int fl = tid & 63;         // f within tile
  for (int f0 = 0; f0 < MM; f0 += 64) {
#pragma unroll
    for (int i = 0; i < 8; ++i) {
      int e = tid + i * 256;        // 0..2047 float4s
      int f = e >> 5, d4 = (e & 31) * 4;
      float4 v = *(const float4*)&mem[(size_t)(f0 + f) * HH + d4];
      *(float4*)&memt[f][d4] = v;
    }
    __syncthreads();
    float s0 = 0.f, s1 = 0.f, s2 = 0.f, s3 = 0.f;
#pragma unroll 8
    for (int d4 = 0; d4 < 128; d4 += 4) {
      float4 m4 = *(const float4*)&memt[fl][d4];
      float4 r0 = *(const float4*)&rloc[rb + 0][d4];
      float4 r1 = *(const float4*)&rloc[rb + 1][d4];
      float4 r2v = *(const float4*)&rloc[rb + 2][d4];
      float4 r3 = *(const float4*)&rloc[rb + 3][d4];
      s0 += m4.x * r0.x + m4.y * r0.y + m4.z * r0.z + m4.w * r0.w;
      s1 += m4.x * r1.x + m4.y * r1.y + m4.z * r1.z + m4.w * r1.w;
      s2 += m4.x * r2v.x + m4.y * r2v.y + m4.z * r2v.z + m4.w * r2v.w;
      s3 += m4.x * r3.x + m4.y * r3.y + m4.z * r3.z + m4.w * r3.w;
    }
    sc[rb + 0][f0 + fl] = s0;
    sc[rb + 1][f0 + fl] = s1;
    sc[rb + 2][f0 + fl] = s2;
    sc[rb + 3][f0 + fl] = s3;
    __syncthreads();
  }

  // ---- softmax over 512, 16 threads per row ----
  int row = tid >> 4, slot = tid & 15;
  float mx = -1e30f;
#pragma unroll
  for (int k = 0; k < 32; ++k) mx = fmaxf(mx, sc[row][slot + 16 * k]);
  red[row][slot] = mx;
  __syncthreads();
  if (slot == 0) {
    float m2 = red[row][0];
    for (int k = 1; k < 16; ++k) m2 = fmaxf(m2, red[row][k]);
    red[row][16] = m2;
  }
  __syncthreads();
  float rowmax = red[row][16];
  float psum = 0.f;
#pragma unroll
  for (int k = 0; k < 32; ++k) {
    int f = slot + 16 * k;
    float e = __expf(sc[row][f] - rowmax);
    sc[row][f] = e;
    psum += e;
  }
  __syncthreads();
  red[row][slot] = psum;
  __syncthreads();
  if (slot == 0) {
    float s = 0.f;
    for (int k = 0; k < 16; ++k) s += red[row][k];
    red[row][16] = 1.f / s;
  }
  __syncthreads();
  float inv = red[row][16];

  // ---- output: out[r][d] = inv * sum_f e[r][f] * mem[f][d] ----
  int d0 = slot * 8;
  float acc[8] = {0.f};
  for (int f0 = 0; f0 < MM; f0 += 64) {
#pragma unroll
    for (int i = 0; i < 8; ++i) {
      int e = tid + i * 256;
      int f = e >> 5, d4 = (e & 31) * 4;
      float4 v = *(const float4*)&mem[(size_t)(f0 + f) * HH + d4];
      *(float4*)&memt[f][d4] = v;
    }
    __syncthreads();
#pragma unroll 4
    for (int f = 0; f < 64; ++f) {
      float a = sc[row][f0 + f];
      float4 m0 = *(const float4*)&memt[f][d0];
      float4 m1 = *(const float4*)&memt[f][d0 + 4];
      acc[0] = fmaf(a, m0.x, acc[0]);
      acc[1] = fmaf(a, m0.y, acc[1]);
      acc[2] = fmaf(a, m0.z, acc[2]);
      acc[3] = fmaf(a, m0.w, acc[3]);
      acc[4] = fmaf(a, m1.x, acc[4]);
      acc[5] = fmaf(a, m1.y, acc[5]);
      acc[6] = fmaf(a, m1.z, acc[6]);
      acc[7] = fmaf(a, m1.w, acc[7]);
    }
    __syncthreads();
  }
  float4 o0 = make_float4(acc[0] * inv, acc[1] * inv, acc[2] * inv, acc[3] * inv);
  float4 o1 = make_float4(acc[4] * inv, acc[5] * inv, acc[6] * inv, acc[7] * inv);
  size_t ob = (size_t)(n0 + row) * 256 + d0;
  *(float4*)&r2[ob] = o0;
  *(float4*)&r2[ob + 4] = o1;
}

// ---------------------------------------------------------------------------
// Kernel 4: fused dual-branch GEMM2 + bias + add + transposed store.
//   out[b,p,c] = sum_k r2s[b*C+c,k]*Ws2[p,k] + sum_k r2t[...]*Wt2[p,k]
//                + bs2[p] + bt2[p]
// ---------------------------------------------------------------------------
__global__ __launch_bounds__(256) void gemm2_kernel(
    const float* __restrict__ r2s, const float* __restrict__ r2t,
    const float* __restrict__ Ws2, const float* __restrict__ Wt2,
    const float* __restrict__ bs2, const float* __restrict__ bt2,
    float* __restrict__ out) {
  int b = blockIdx.z;
  int c0 = blockIdx.x * 64;
  int p0 = blockIdx.y * 64;
  __shared__ float As[16][68];
  __shared__ float At[16][68];
  __shared__ float Bs[16][68];
  __shared__ float Bt[16][68];
  int tid = threadIdx.x;
  int tx = tid & 15, ty = tid >> 4;
  int lr = tid >> 2;           // 0..63
  int lk = (tid & 3) * 4;      // 0,4,8,12
  float acc[4][4] = {{0.f}};

  for (int k0 = 0; k0 < 256; k0 += 16) {
    {
      int c = c0 + lr;
      float4 a4s = make_float4(0, 0, 0, 0), a4t = a4s;
      if (c < CC) {
        size_t base = ((size_t)b * CC + c) * 256 + k0 + lk;
        a4s = *(const float4*)(r2s + base);
        a4t = *(const float4*)(r2t + base);
      }
      As[lk + 0][lr] = a4s.x; As[lk + 1][lr] = a4s.y;
      As[lk + 2][lr] = a4s.z; As[lk + 3][lr] = a4s.w;
      At[lk + 0][lr] = a4t.x; At[lk + 1][lr] = a4t.y;
      At[lk + 2][lr] = a4t.z; At[lk + 3][lr] = a4t.w;
      int p = p0 + lr;
      float4 b4s = make_float4(0, 0, 0, 0), b4t = b4s;
      if (p < PP) {
        size_t base = (size_t)p * 256 + k0 + lk;
        b4s = *(const float4*)(Ws2 + base);
        b4t = *(const float4*)(Wt2 + base);
      }
      Bs[lk + 0][lr] = b4s.x; Bs[lk + 1][lr] = b4s.y;
      Bs[lk + 2][lr] = b4s.z; Bs[lk + 3][lr] = b4s.w;
      Bt[lk + 0][lr] = b4t.x; Bt[lk + 1][lr] = b4t.y;
      Bt[lk + 2][lr] = b4t.z; Bt[lk + 3][lr] = b4t.w;
    }
    __syncthreads();
#pragma unroll
    for (int k = 0; k < 16; ++k) {
      float4 as4 = *(const float4*)&As[k][tx * 4];
      float4 at4 = *(const float4*)&At[k][tx * 4];
      float4 bs4 = *(const float4*)&Bs[k][ty * 4];
      float4 bt4 = *(const float4*)&Bt[k][ty * 4];
      float av_s[4] = {as4.x, as4.y, as4.z, as4.w};
      float av_t[4] = {at4.x, at4.y, at4.z, at4.w};
      float bv_s[4] = {bs4.x, bs4.y, bs4.z, bs4.w};
      float bv_t[4] = {bt4.x, bt4.y, bt4.z, bt4.w};
#pragma unroll
      for (int i = 0; i < 4; ++i)
#pragma unroll
        for (int j = 0; j < 4; ++j) {
          acc[i][j] = fmaf(av_s[i], bv_s[j], acc[i][j]);
          acc[i][j] = fmaf(av_t[i], bv_t[j], acc[i][j]);
        }
    }
    __syncthreads();
  }

#pragma unroll
  for (int j = 0; j < 4; ++j) {
    int p = p0 + ty * 4 + j;
    if (p >= PP) continue;
    float bias = bs2[p] + bt2[p];
    size_t rowbase = ((size_t)b * PP + p) * CC;
#pragma unroll
    for (int i = 0; i < 4; ++i) {
      int c = c0 + tx * 4 + i;
      if (c < CC) out[rowbase + c] = acc[i][j] + bias;
    }
  }
}

// ---------------------------------------------------------------------------
extern "C" void kernel_launch(void* const* d_in, const int* in_sizes, int n_in,
                              void* d_out, int out_size, void* d_ws, size_t ws_size,
                              hipStream_t stream) {
  const float* x    = (const float*)d_in[0];
  const float* Ws1  = (const float*)d_in[1];
  const float* bs1  = (const float*)d_in[2];
  const float* Ws2  = (const float*)d_in[3];
  const float* bs2  = (const float*)d_in[4];
  const float* Wt1  = (const float*)d_in[5];
  const float* bt1  = (const float*)d_in[6];
  const float* Wt2  = (const float*)d_in[7];
  const float* bt2  = (const float*)d_in[8];
  const float* memS = (const float*)d_in[9];
  const float* memT = (const float*)d_in[10];
  float* out = (float*)d_out;

  const size_t N = (size_t)BB * CC;          // 41088
  float* ws    = (float*)d_ws;
  float* r2s   = ws;                         // [N,256]
  float* r2t   = r2s + N * 256;              // [N,256]
  float* BsEff = r2t + N * 256;              // [L,H]
  float* BtEff = BsEff + (size_t)LL * HH;    // [L,H]
  // total: (2*N*256 + 2*L*H)*4 bytes ~= 85 MB

  // 1. smeared weights
  weff_kernel<<<(LL * HH + 255) / 256, 256, 0, stream>>>(Ws1, Wt1, BsEff, BtEff);

  // 2. GEMM1 + sigmoid (both branches)
  dim3 g1((CC + 63) / 64, HH / 64, BB);
  gemm1_kernel<<<g1, 256, 0, stream>>>(x, BsEff, BtEff, bs1, bt1, r2s, r2t);

  // 3. memory enhance per branch
  int nblk = (int)(N / 16);                  // 2568, exact
  memenh_kernel<<<nblk, 256, 0, stream>>>(memS, r2s);
  memenh_kernel<<<nblk, 256, 0, stream>>>(memT, r2t);

  // 4. GEMM2 + bias + add + transpose-store
  dim3 g2((CC + 63) / 64, (PP + 63) / 64, BB);
  gemm2_kernel<<<g2, 256, 0, stream>>>(r2s, r2t, Ws2, Wt2, bs2, bt2, out);
}

// Round 2
// 756.872 us; speedup vs baseline: 2.1698x; 2.1698x over previous
//
#include <hip/hip_runtime.h>
#include <math.h>

#define BB 128
#define LL 720
#define CC 321
#define HH 128
#define PP 336
#define MM 512

typedef __attribute__((ext_vector_type(8))) short bf16x8;
typedef __attribute__((ext_vector_type(4))) float f32x4;

__device__ __forceinline__ short f2bf(float x) {
  unsigned u = __builtin_bit_cast(unsigned, x);
  u = (u + 0x7FFFu + ((u >> 16) & 1u)) >> 16;
  return (short)u;
}

// load an 8-element bf16 MFMA fragment: elems 0..3 at p, 4..7 at p+16
__device__ __forceinline__ bf16x8 ldfrag(const short* p) {
  short4 a = *(const short4*)p;
  short4 b = *(const short4*)(p + 16);
  bf16x8 r;
  r[0] = a.x; r[1] = a.y; r[2] = a.z; r[3] = a.w;
  r[4] = b.x; r[5] = b.y; r[6] = b.z; r[7] = b.w;
  return r;
}

// ---------------------------------------------------------------------------
// Kernel 1: effective (smeared) weights (moving-average folded into W1).
// ---------------------------------------------------------------------------
__global__ void weff_kernel(const float* __restrict__ Ws1,
                            const float* __restrict__ Wt1,
                            float* __restrict__ BsEff,
                            float* __restrict__ BtEff) {
  int idx = blockIdx.x * 256 + threadIdx.x;
  if (idx >= LL * HH) return;
  int h = idx % HH, j = idx / HH;
  float ss = 0.f, st = 0.f;
  if (j == 0) {
    for (int l = 0; l <= 12; ++l) {
      float w = 13.f - (float)l;
      ss += w * Ws1[h * LL + l];
      st += w * Wt1[h * LL + l];
    }
  } else if (j == LL - 1) {
    for (int d = 0; d <= 12; ++d) {
      float w = 13.f - (float)d;
      ss += w * Ws1[h * LL + LL - 1 - d];
      st += w * Wt1[h * LL + LL - 1 - d];
    }
  } else {
    int lo = j - 12 < 0 ? 0 : j - 12;
    int hi = j + 12 > LL - 1 ? LL - 1 : j + 12;
    for (int l = lo; l <= hi; ++l) {
      ss += Ws1[h * LL + l];
      st += Wt1[h * LL + l];
    }
  }
  ss *= (1.f / 25.f);
  st *= (1.f / 25.f);
  BsEff[idx] = Ws1[h * LL + j] - ss;
  BtEff[idx] = st;
}

// ---------------------------------------------------------------------------
// Kernel 2: fused dual-branch GEMM1 + sigmoid.
//   Writes fp32 R into r2[:,128..255] AND a packed bf16 copy of R into the
//   first 256 bytes of each r2 row (floats 0..63) for the MFMA attention.
// ---------------------------------------------------------------------------
__global__ __launch_bounds__(256) void gemm1_kernel(
    const float* __restrict__ x,
    const float* __restrict__ BsEff, const float* __restrict__ BtEff,
    const float* __restrict__ bs1, const float* __restrict__ bt1,
    float* __restrict__ r2s, float* __restrict__ r2t) {
  int b = blockIdx.z;
  int c0 = blockIdx.x * 64;
  int h0 = blockIdx.y * 64;
  __shared__ float xs[16][64];
  __shared__ float ws[16][64];
  __shared__ float wt[16][64];
  int tid = threadIdx.x;
  int tx = tid & 15, ty = tid >> 4;
  float accS[4][4] = {{0.f}}, accT[4][4] = {{0.f}};
  const float* xb = x + (size_t)b * LL * CC;

  for (int l0 = 0; l0 < LL; l0 += 16) {
#pragma unroll
    for (int i = 0; i < 4; ++i) {
      int e = tid + i * 256;
      int kl = e >> 6, q = e & 63;
      int c = c0 + q;
      xs[kl][q] = (c < CC) ? xb[(size_t)(l0 + kl) * CC + c] : 0.f;
      ws[kl][q] = BsEff[(l0 + kl) * HH + h0 + q];
      wt[kl][q] = BtEff[(l0 + kl) * HH + h0 + q];
    }
    __syncthreads();
#pragma unroll
    for (int kl = 0; kl < 16; ++kl) {
      float4 a4 = *(const float4*)&xs[kl][tx * 4];
      float4 s4 = *(const float4*)&ws[kl][ty * 4];
      float4 t4 = *(const float4*)&wt[kl][ty * 4];
      float a[4] = {a4.x, a4.y, a4.z, a4.w};
      float bsv[4] = {s4.x, s4.y, s4.z, s4.w};
      float btv[4] = {t4.x, t4.y, t4.z, t4.w};
#pragma unroll
      for (int i = 0; i < 4; ++i)
#pragma unroll
        for (int j = 0; j < 4; ++j) {
          accS[i][j] = fmaf(a[i], bsv[j], accS[i][j]);
          accT[i][j] = fmaf(a[i], btv[j], accT[i][j]);
        }
    }
    __syncthreads();
  }

#pragma unroll
  for (int i = 0; i < 4; ++i) {
    int c = c0 + tx * 4 + i;
    if (c >= CC) continue;
    size_t n = (size_t)b * CC + c;
    float4 vs, vt;
    float* pvs = &vs.x;
    float* pvt = &vt.x;
#pragma unroll
    for (int j = 0; j < 4; ++j) {
      int h = h0 + ty * 4 + j;
      float es = accS[i][j] + bs1[h];
      float et = accT[i][j] + bt1[h];
      pvs[j] = 1.f / (1.f + __expf(-es));
      pvt[j] = 1.f / (1.f + __expf(-et));
    }
    *(float4*)&r2s[n * 256 + 128 + h0 + ty * 4] = vs;
    *(float4*)&r2t[n * 256 + 128 + h0 + ty * 4] = vt;
    short4 svs = make_short4(f2bf(vs.x), f2bf(vs.y), f2bf(vs.z), f2bf(vs.w));
    short4 svt = make_short4(f2bf(vt.x), f2bf(vt.y), f2bf(vt.z), f2bf(vt.w));
    *(short4*)((short*)(r2s + n * 256) + h0 + ty * 4) = svs;
    *(short4*)((short*)(r2t + n * 256) + h0 + ty * 4) = svt;
  }
}

// ---------------------------------------------------------------------------
// Kernel 2b: convert mem (fp32 [512][128]) to bf16 natural + transposed.
// ---------------------------------------------------------------------------
__global__ void memcvt_kernel(const float* __restrict__ memS,
                              const float* __restrict__ memT,
                              short* __restrict__ mSb, short* __restrict__ mSTb,
                              short* __restrict__ mTb, short* __restrict__ mTTb) {
  int i = blockIdx.x * 256 + threadIdx.x;
  if (i >= MM * HH) return;
  int f = i >> 7, d = i & 127;
  short vs = f2bf(memS[i]);
  short vt = f2bf(memT[i]);
  mSb[i] = vs;
  mSTb[d * MM + f] = vs;
  mTb[i] = vt;
  mTTb[d * MM + f] = vt;
}

// ---------------------------------------------------------------------------
// Kernel 3: MFMA memory-enhance. 32 rows/block, 4 waves, 256 threads.
//   Wave w owns f-slice [w*128, w*128+128).
//   Phase 1: S^T = mem . R^T  (16x16x32 bf16 MFMA, C-frag rows = f)
//   Phase 2: in-register softmax (shfl + tiny LDS cross-wave exchange)
//   Phase 3: O^T = mem^T . P^T (P^T frags == exp'd C-frags, zero movement)
//   Phase 4: cross-wave O reduction in LDS, normalize, store fp32.
// ---------------------------------------------------------------------------
__global__ __launch_bounds__(256) void memenh_mfma(
    const short* __restrict__ memb,   // [512][128] bf16
    const short* __restrict__ memTb,  // [128][512] bf16
    float* __restrict__ r2) {
  int n0 = blockIdx.x * 32;
  int tid = threadIdx.x;
  int w = tid >> 6;
  int l = tid & 63;
  int lr = l & 15;
  int lg = l >> 4;

  __shared__ float pmax_lds[4][32];
  __shared__ float psum_lds[4][32];
  __shared__ float opart[2][32 * 132];

  // --- B-frags: R rows (bf16 packed in first 256 bytes of each r2 row) ---
  bf16x8 brag[2][4];
#pragma unroll
  for (int rt = 0; rt < 2; ++rt) {
    const short* rb = (const short*)(r2 + (size_t)(n0 + lr + 16 * rt) * 256);
#pragma unroll
    for (int k = 0; k < 4; ++k) brag[rt][k] = ldfrag(rb + k * 32 + lg * 4);
  }

  // --- Phase 1: S^T = mem . R^T ---
  f32x4 accS[2][8];
#pragma unroll
  for (int ft = 0; ft < 8; ++ft) {
    f32x4 a0 = {0.f, 0.f, 0.f, 0.f}, a1 = {0.f, 0.f, 0.f, 0.f};
    const short* mrow = memb + (size_t)(w * 128 + ft * 16 + lr) * 128;
#pragma unroll
    for (int k = 0; k < 4; ++k) {
      bf16x8 af = ldfrag(mrow + k * 32 + lg * 4);
      a0 = __builtin_amdgcn_mfma_f32_16x16x32_bf16(af, brag[0][k], a0, 0, 0, 0);
      a1 = __builtin_amdgcn_mfma_f32_16x16x32_bf16(af, brag[1][k], a1, 0, 0, 0);
    }
    accS[0][ft] = a0;
    accS[1][ft] = a1;
  }

  // --- Phase 2: softmax along f (rows r = lr + 16*rt) ---
#pragma unroll
  for (int rt = 0; rt < 2; ++rt) {
    float mx = -3.4e38f;
#pragma unroll
    for (int ft = 0; ft < 8; ++ft) {
      f32x4 v = accS[rt][ft];
      mx = fmaxf(mx, fmaxf(fmaxf(v[0], v[1]), fmaxf(v[2], v[3])));
    }
    mx = fmaxf(mx, __shfl_xor(mx, 16));
    mx = fmaxf(mx, __shfl_xor(mx, 32));
    if (lg == 0) pmax_lds[w][rt * 16 + lr] = mx;
  }
  __syncthreads();
#pragma unroll
  for (int rt = 0; rt < 2; ++rt) {
    float gm = fmaxf(fmaxf(pmax_lds[0][rt * 16 + lr], pmax_lds[1][rt * 16 + lr]),
                     fmaxf(pmax_lds[2][rt * 16 + lr], pmax_lds[3][rt * 16 + lr]));
    float s = 0.f;
#pragma unroll
    for (int ft = 0; ft < 8; ++ft) {
      f32x4 v = accS[rt][ft];
#pragma unroll
      for (int j = 0; j < 4; ++j) {
        float e = __expf(v[j] - gm);
        v[j] = e;
        s += e;
      }
      accS[rt][ft] = v;
    }
    s += __shfl_xor(s, 16);
    s += __shfl_xor(s, 32);
    if (lg == 0) psum_lds[w][rt * 16 + lr] = s;
  }

  // --- P^T -> bf16 PV B-frags (pure in-lane conversion) ---
  bf16x8 pb[2][4];
#pragma unroll
  for (int rt = 0; rt < 2; ++rt)
#pragma unroll
    for (int t = 0; t < 4; ++t) {
      f32x4 e0 = accS[rt][2 * t], e1 = accS[rt][2 * t + 1];
      bf16x8 f;
      f[0] = f2bf(e0[0]); f[1] = f2bf(e0[1]); f[2] = f2bf(e0[2]); f[3] = f2bf(e0[3]);
      f[4] = f2bf(e1[0]); f[5] = f2bf(e1[1]); f[6] = f2bf(e1[2]); f[7] = f2bf(e1[3]);
      pb[rt][t] = f;
    }

  // --- Phase 3: O^T partial = mem^T . P^T over wave's f-slice ---
  f32x4 accO[8][2];
#pragma unroll
  for (int dt = 0; dt < 8; ++dt) {
    f32x4 o0 = {0.f, 0.f, 0.f, 0.f}, o1 = {0.f, 0.f, 0.f, 0.f};
    const short* mT = memTb + (size_t)(dt * 16 + lr) * MM + w * 128;
#pragma unroll
    for (int t = 0; t < 4; ++t) {
      bf16x8 af = ldfrag(mT + t * 32 + lg * 4);
      o0 = __builtin_amdgcn_mfma_f32_16x16x32_bf16(af, pb[0][t], o0, 0, 0, 0);
      o1 = __builtin_amdgcn_mfma_f32_16x16x32_bf16(af, pb[1][t], o1, 0, 0, 0);
    }
    accO[dt][0] = o0;
    accO[dt][1] = o1;
  }

  // --- Phase 4: pairwise cross-wave reduction ---
  // waves 2,3 dump partials; waves 0,1 add theirs; then final combine.
  if (w >= 2) {
#pragma unroll
    for (int dt = 0; dt < 8; ++dt)
#pragma unroll
      for (int rt = 0; rt < 2; ++rt) {
        f32x4 o = accO[dt][rt];
        *(float4*)&opart[w - 2][(lr + 16 * rt) * 132 + dt * 16 + lg * 4] =
            make_float4(o[0], o[1], o[2], o[3]);
      }
  }
  __syncthreads();
  if (w < 2) {
#pragma unroll
    for (int dt = 0; dt < 8; ++dt)
#pragma unroll
      for (int rt = 0; rt < 2; ++rt) {
        float* p = &opart[w][(lr + 16 * rt) * 132 + dt * 16 + lg * 4];
        float4 q = *(const float4*)p;
        f32x4 o = accO[dt][rt];
        *(float4*)p = make_float4(o[0] + q.x, o[1] + q.y, o[2] + q.z, o[3] + q.w);
      }
  }
  __syncthreads();

  // --- normalize + store O to r2[:,0..127] (fp32) ---
#pragma unroll
  for (int i = 0; i < 4; ++i) {
    int pos = tid + i * 256;          // 0..1023 float4 slots
    int r = pos >> 5, s4 = (pos & 31) * 4;
    float inv = 1.f / (((psum_lds[0][r] + psum_lds[1][r]) + psum_lds[2][r]) +
                       psum_lds[3][r]);
    float4 a = *(const float4*)&opart[0][r * 132 + s4];
    float4 b = *(const float4*)&opart[1][r * 132 + s4];
    *(float4*)&r2[(size_t)(n0 + r) * 256 + s4] =
        make_float4((a.x + b.x) * inv, (a.y + b.y) * inv, (a.z + b.z) * inv,
                    (a.w + b.w) * inv);
  }
}

// ---------------------------------------------------------------------------
// Kernel 4: fused dual-branch GEMM2 + bias + add + transposed store.
// ---------------------------------------------------------------------------
__global__ __launch_bounds__(256) void gemm2_kernel(
    const float* __restrict__ r2s, const float* __restrict__ r2t,
    const float* __restrict__ Ws2, const float* __restrict__ Wt2,
    const float* __restrict__ bs2, const float* __restrict__ bt2,
    float* __restrict__ out) {
  int b = blockIdx.z;
  int c0 = blockIdx.x * 64;
  int p0 = blockIdx.y * 64;
  __shared__ float As[16][68];
  __shared__ float At[16][68];
  __shared__ float Bs[16][68];
  __shared__ float Bt[16][68];
  int tid = threadIdx.x;
  int tx = tid & 15, ty = tid >> 4;
  int lr = tid >> 2;
  int lk = (tid & 3) * 4;
  float acc[4][4] = {{0.f}};

  for (int k0 = 0; k0 < 256; k0 += 16) {
    {
      int c = c0 + lr;
      float4 a4s = make_float4(0, 0, 0, 0), a4t = a4s;
      if (c < CC) {
        size_t base = ((size_t)b * CC + c) * 256 + k0 + lk;
        a4s = *(const float4*)(r2s + base);
        a4t = *(const float4*)(r2t + base);
      }
      As[lk + 0][lr] = a4s.x; As[lk + 1][lr] = a4s.y;
      As[lk + 2][lr] = a4s.z; As[lk + 3][lr] = a4s.w;
      At[lk + 0][lr] = a4t.x; At[lk + 1][lr] = a4t.y;
      At[lk + 2][lr] = a4t.z; At[lk + 3][lr] = a4t.w;
      int p = p0 + lr;
      float4 b4s = make_float4(0, 0, 0, 0), b4t = b4s;
      if (p < PP) {
        size_t base = (size_t)p * 256 + k0 + lk;
        b4s = *(const float4*)(Ws2 + base);
        b4t = *(const float4*)(Wt2 + base);
      }
      Bs[lk + 0][lr] = b4s.x; Bs[lk + 1][lr] = b4s.y;
      Bs[lk + 2][lr] = b4s.z; Bs[lk + 3][lr] = b4s.w;
      Bt[lk + 0][lr] = b4t.x; Bt[lk + 1][lr] = b4t.y;
      Bt[lk + 2][lr] = b4t.z; Bt[lk + 3][lr] = b4t.w;
    }
    __syncthreads();
#pragma unroll
    for (int k = 0; k < 16; ++k) {
      float4 as4 = *(const float4*)&As[k][tx * 4];
      float4 at4 = *(const float4*)&At[k][tx * 4];
      float4 bs4 = *(const float4*)&Bs[k][ty * 4];
      float4 bt4 = *(const float4*)&Bt[k][ty * 4];
      float av_s[4] = {as4.x, as4.y, as4.z, as4.w};
      float av_t[4] = {at4.x, at4.y, at4.z, at4.w};
      float bv_s[4] = {bs4.x, bs4.y, bs4.z, bs4.w};
      float bv_t[4] = {bt4.x, bt4.y, bt4.z, bt4.w};
#pragma unroll
      for (int i = 0; i < 4; ++i)
#pragma unroll
        for (int j = 0; j < 4; ++j) {
          acc[i][j] = fmaf(av_s[i], bv_s[j], acc[i][j]);
          acc[i][j] = fmaf(av_t[i], bv_t[j], acc[i][j]);
        }
    }
    __syncthreads();
  }

#pragma unroll
  for (int j = 0; j < 4; ++j) {
    int p = p0 + ty * 4 + j;
    if (p >= PP) continue;
    float bias = bs2[p] + bt2[p];
    size_t rowbase = ((size_t)b * PP + p) * CC;
#pragma unroll
    for (int i = 0; i < 4; ++i) {
      int c = c0 + tx * 4 + i;
      if (c < CC) out[rowbase + c] = acc[i][j] + bias;
    }
  }
}

// ---------------------------------------------------------------------------
extern "C" void kernel_launch(void* const* d_in, const int* in_sizes, int n_in,
                              void* d_out, int out_size, void* d_ws, size_t ws_size,
                              hipStream_t stream) {
  const float* x    = (const float*)d_in[0];
  const float* Ws1  = (const float*)d_in[1];
  const float* bs1  = (const float*)d_in[2];
  const float* Ws2  = (const float*)d_in[3];
  const float* bs2  = (const float*)d_in[4];
  const float* Wt1  = (const float*)d_in[5];
  const float* bt1  = (const float*)d_in[6];
  const float* Wt2  = (const float*)d_in[7];
  const float* bt2  = (const float*)d_in[8];
  const float* memS = (const float*)d_in[9];
  const float* memT = (const float*)d_in[10];
  float* out = (float*)d_out;

  const size_t N = (size_t)BB * CC;          // 41088
  float* ws    = (float*)d_ws;
  float* r2s   = ws;                         // [N,256]
  float* r2t   = r2s + N * 256;              // [N,256]
  float* BsEff = r2t + N * 256;              // [L,H] (later reused for bf16 mem)
  float* BtEff = BsEff + (size_t)LL * HH;    // [L,H]

  // bf16 mem buffers carved out of the (dead-after-gemm1) BsEff/BtEff space:
  // need 2*65536 shorts = 256KB each; BsEff/BtEff are 368KB each.
  short* mSb  = (short*)BsEff;
  short* mSTb = mSb + (size_t)MM * HH;
  short* mTb  = (short*)BtEff;
  short* mTTb = mTb + (size_t)MM * HH;

  // 1. smeared weights
  weff_kernel<<<(LL * HH + 255) / 256, 256, 0, stream>>>(Ws1, Wt1, BsEff, BtEff);

  // 2. GEMM1 + sigmoid (both branches), emits fp32 R + packed bf16 R
  dim3 g1((CC + 63) / 64, HH / 64, BB);
  gemm1_kernel<<<g1, 256, 0, stream>>>(x, BsEff, BtEff, bs1, bt1, r2s, r2t);

  // 2b. mem -> bf16 (natural + transposed); clobbers BsEff/BtEff (now dead)
  memcvt_kernel<<<(MM * HH + 255) / 256, 256, 0, stream>>>(memS, memT, mSb, mSTb,
                                                           mTb, mTTb);

  // 3. MFMA memory enhance per branch (N/32 = 1284 blocks)
  int nblk = (int)(N / 32);
  memenh_mfma<<<nblk, 256, 0, stream>>>(mSb, mSTb, r2s);
  memenh_mfma<<<nblk, 256, 0, stream>>>(mTb, mTTb, r2t);

  // 4. GEMM2 + bias + add + transpose-store
  dim3 g2((CC + 63) / 64, (PP + 63) / 64, BB);
  gemm2_kernel<<<g2, 256, 0, stream>>>(r2s, r2t, Ws2, Wt2, bs2, bt2, out);
}

// Round 3
// 704.801 us; speedup vs baseline: 2.3301x; 1.0739x over previous
//
#include <hip/hip_runtime.h>
#include <math.h>

#define BB 128
#define LL 720
#define CC 321
#define HH 128
#define PP 336
#define MM 512
#define LPAD 736  // 720 padded to multiple of 32

typedef __attribute__((ext_vector_type(8))) short bf16x8;
typedef __attribute__((ext_vector_type(4))) float f32x4;

__device__ __forceinline__ short f2bf(float x) {
  unsigned u = __builtin_bit_cast(unsigned, x);
  u = (u + 0x7FFFu + ((u >> 16) & 1u)) >> 16;
  return (short)u;
}

// load an 8-element bf16 MFMA fragment: elems 0..3 at p, 4..7 at p+16
__device__ __forceinline__ bf16x8 ldfrag(const short* p) {
  short4 a = *(const short4*)p;
  short4 b = *(const short4*)(p + 16);
  bf16x8 r;
  r[0] = a.x; r[1] = a.y; r[2] = a.z; r[3] = a.w;
  r[4] = b.x; r[5] = b.y; r[6] = b.z; r[7] = b.w;
  return r;
}

// ---------------------------------------------------------------------------
// Kernel 1: effective (smeared) weights, folded moving-average, emitted as
// bf16 in [H][LPAD] layout (K-contiguous rows, zero-padded 720..735).
//   BsEff[h,j] = Ws1[h,j] - smear(Ws1)[h,j]   (seasonal: x - trend)
//   BtEff[h,j] = smear(Wt1)[h,j]              (trend)
// ---------------------------------------------------------------------------
__global__ void weff_kernel(const float* __restrict__ Ws1,
                            const float* __restrict__ Wt1,
                            short* __restrict__ WsT,
                            short* __restrict__ WtT) {
  int idx = blockIdx.x * 256 + threadIdx.x;
  if (idx >= HH * LPAD) return;
  int j = idx % LPAD, h = idx / LPAD;
  if (j >= LL) { WsT[idx] = 0; WtT[idx] = 0; return; }
  float ss = 0.f, st = 0.f;
  if (j == 0) {
    for (int l = 0; l <= 12; ++l) {
      float w = 13.f - (float)l;
      ss += w * Ws1[h * LL + l];
      st += w * Wt1[h * LL + l];
    }
  } else if (j == LL - 1) {
    for (int d = 0; d <= 12; ++d) {
      float w = 13.f - (float)d;
      ss += w * Ws1[h * LL + LL - 1 - d];
      st += w * Wt1[h * LL + LL - 1 - d];
    }
  } else {
    int lo = j - 12 < 0 ? 0 : j - 12;
    int hi = j + 12 > LL - 1 ? LL - 1 : j + 12;
    for (int l = lo; l <= hi; ++l) {
      ss += Ws1[h * LL + l];
      st += Wt1[h * LL + l];
    }
  }
  ss *= (1.f / 25.f);
  st *= (1.f / 25.f);
  WsT[idx] = f2bf(Ws1[h * LL + j] - ss);
  WtT[idx] = f2bf(st);
}

// ---------------------------------------------------------------------------
// Kernel 2: MFMA dual-branch GEMM1 + sigmoid. No LDS.
//   Block: 64 c-rows x all 128 h, one batch b. 4 waves, wave w owns 16 c.
//   D[h][c] = Weff[h][:] . x[b][:][c]  via mfma_16x16x32_bf16:
//     A-frag: Weff rows (K-contiguous, direct global)
//     B-frag: x columns (8 strided scalar loads/lane, cvt bf16 in-reg)
//   Epilogue: +bias, sigmoid, store fp32 R into r2[:,128..255] and packed
//   bf16 R into first 256B of each row (for the MFMA attention).
// ---------------------------------------------------------------------------
__global__ __launch_bounds__(256) void gemm1_mfma(
    const float* __restrict__ x,
    const short* __restrict__ WsT, const short* __restrict__ WtT,
    const float* __restrict__ bs1, const float* __restrict__ bt1,
    float* __restrict__ r2s, float* __restrict__ r2t) {
  int b = blockIdx.y;
  int c0 = blockIdx.x * 64;
  int tid = threadIdx.x;
  int w = tid >> 6, l = tid & 63, lr = l & 15, lg = l >> 4;
  int c = c0 + w * 16 + lr;
  int c_eff = c < CC ? c : CC - 1;
  const float* xb = x + (size_t)b * LL * CC + c_eff;

  f32x4 accS[8], accT[8];
#pragma unroll
  for (int i = 0; i < 8; ++i) {
    accS[i] = (f32x4){0.f, 0.f, 0.f, 0.f};
    accT[i] = (f32x4){0.f, 0.f, 0.f, 0.f};
  }

  const short* wsBase = WsT + lr * LPAD + lg * 4;
  const short* wtBase = WtT + lr * LPAD + lg * 4;

  for (int k0 = 0; k0 < LL; k0 += 32) {
    // B-frag: x[k][c], k = k0+lg*4+j (elems 0..3) and +16 (elems 4..7)
    bf16x8 bx;
#pragma unroll
    for (int j = 0; j < 4; ++j) {
      int k1 = k0 + lg * 4 + j;
      int k2 = k1 + 16;
      float v1 = xb[(size_t)k1 * CC];                    // k1 <= 719 always
      float v2 = (k2 < LL) ? xb[(size_t)k2 * CC] : 0.f;  // pad tail
      bx[j] = f2bf(v1);
      bx[j + 4] = f2bf(v2);
    }
#pragma unroll
    for (int ht = 0; ht < 8; ++ht) {
      bf16x8 aS = ldfrag(wsBase + (size_t)ht * 16 * LPAD + k0);
      bf16x8 aT = ldfrag(wtBase + (size_t)ht * 16 * LPAD + k0);
      accS[ht] = __builtin_amdgcn_mfma_f32_16x16x32_bf16(aS, bx, accS[ht], 0, 0, 0);
      accT[ht] = __builtin_amdgcn_mfma_f32_16x16x32_bf16(aT, bx, accT[ht], 0, 0, 0);
    }
  }

  if (c < CC) {
    size_t n = (size_t)b * CC + c;
    float* rowS = r2s + n * 256;
    float* rowT = r2t + n * 256;
#pragma unroll
    for (int ht = 0; ht < 8; ++ht) {
      int h = ht * 16 + lg * 4;  // D row = (lane>>4)*4 + reg (m89 layout)
      float4 bS = *(const float4*)&bs1[h];
      float4 bT = *(const float4*)&bt1[h];
      float4 vs, vt;
      float* ps = &vs.x;
      float* pt = &vt.x;
      const float* pbS = &bS.x;
      const float* pbT = &bT.x;
#pragma unroll
      for (int j = 0; j < 4; ++j) {
        ps[j] = 1.f / (1.f + __expf(-(accS[ht][j] + pbS[j])));
        pt[j] = 1.f / (1.f + __expf(-(accT[ht][j] + pbT[j])));
      }
      *(float4*)&rowS[128 + h] = vs;
      *(float4*)&rowT[128 + h] = vt;
      short4 svs = make_short4(f2bf(vs.x), f2bf(vs.y), f2bf(vs.z), f2bf(vs.w));
      short4 svt = make_short4(f2bf(vt.x), f2bf(vt.y), f2bf(vt.z), f2bf(vt.w));
      *(short4*)((short*)rowS + h) = svs;
      *(short4*)((short*)rowT + h) = svt;
    }
  }
}

// ---------------------------------------------------------------------------
// Kernel 2b: convert mem (fp32 [512][128]) to bf16 natural + transposed.
// ---------------------------------------------------------------------------
__global__ void memcvt_kernel(const float* __restrict__ memS,
                              const float* __restrict__ memT,
                              short* __restrict__ mSb, short* __restrict__ mSTb,
                              short* __restrict__ mTb, short* __restrict__ mTTb) {
  int i = blockIdx.x * 256 + threadIdx.x;
  if (i >= MM * HH) return;
  int f = i >> 7, d = i & 127;
  short vs = f2bf(memS[i]);
  short vt = f2bf(memT[i]);
  mSb[i] = vs;
  mSTb[d * MM + f] = vs;
  mTb[i] = vt;
  mTTb[d * MM + f] = vt;
}

// ---------------------------------------------------------------------------
// Kernel 3: MFMA memory-enhance. 32 rows/block, 4 waves, 256 threads.
// ---------------------------------------------------------------------------
__global__ __launch_bounds__(256) void memenh_mfma(
    const short* __restrict__ memb,   // [512][128] bf16
    const short* __restrict__ memTb,  // [128][512] bf16
    float* __restrict__ r2) {
  int n0 = blockIdx.x * 32;
  int tid = threadIdx.x;
  int w = tid >> 6;
  int l = tid & 63;
  int lr = l & 15;
  int lg = l >> 4;

  __shared__ float pmax_lds[4][32];
  __shared__ float psum_lds[4][32];
  __shared__ float opart[2][32 * 132];

  // --- B-frags: R rows (bf16 packed in first 256 bytes of each r2 row) ---
  bf16x8 brag[2][4];
#pragma unroll
  for (int rt = 0; rt < 2; ++rt) {
    const short* rb = (const short*)(r2 + (size_t)(n0 + lr + 16 * rt) * 256);
#pragma unroll
    for (int k = 0; k < 4; ++k) brag[rt][k] = ldfrag(rb + k * 32 + lg * 4);
  }

  // --- Phase 1: S^T = mem . R^T ---
  f32x4 accS[2][8];
#pragma unroll
  for (int ft = 0; ft < 8; ++ft) {
    f32x4 a0 = {0.f, 0.f, 0.f, 0.f}, a1 = {0.f, 0.f, 0.f, 0.f};
    const short* mrow = memb + (size_t)(w * 128 + ft * 16 + lr) * 128;
#pragma unroll
    for (int k = 0; k < 4; ++k) {
      bf16x8 af = ldfrag(mrow + k * 32 + lg * 4);
      a0 = __builtin_amdgcn_mfma_f32_16x16x32_bf16(af, brag[0][k], a0, 0, 0, 0);
      a1 = __builtin_amdgcn_mfma_f32_16x16x32_bf16(af, brag[1][k], a1, 0, 0, 0);
    }
    accS[0][ft] = a0;
    accS[1][ft] = a1;
  }

  // --- Phase 2: softmax along f (rows r = lr + 16*rt) ---
#pragma unroll
  for (int rt = 0; rt < 2; ++rt) {
    float mx = -3.4e38f;
#pragma unroll
    for (int ft = 0; ft < 8; ++ft) {
      f32x4 v = accS[rt][ft];
      mx = fmaxf(mx, fmaxf(fmaxf(v[0], v[1]), fmaxf(v[2], v[3])));
    }
    mx = fmaxf(mx, __shfl_xor(mx, 16));
    mx = fmaxf(mx, __shfl_xor(mx, 32));
    if (lg == 0) pmax_lds[w][rt * 16 + lr] = mx;
  }
  __syncthreads();
#pragma unroll
  for (int rt = 0; rt < 2; ++rt) {
    float gm = fmaxf(fmaxf(pmax_lds[0][rt * 16 + lr], pmax_lds[1][rt * 16 + lr]),
                     fmaxf(pmax_lds[2][rt * 16 + lr], pmax_lds[3][rt * 16 + lr]));
    float s = 0.f;
#pragma unroll
    for (int ft = 0; ft < 8; ++ft) {
      f32x4 v = accS[rt][ft];
#pragma unroll
      for (int j = 0; j < 4; ++j) {
        float e = __expf(v[j] - gm);
        v[j] = e;
        s += e;
      }
      accS[rt][ft] = v;
    }
    s += __shfl_xor(s, 16);
    s += __shfl_xor(s, 32);
    if (lg == 0) psum_lds[w][rt * 16 + lr] = s;
  }

  // --- P^T -> bf16 PV B-frags (pure in-lane conversion) ---
  bf16x8 pb[2][4];
#pragma unroll
  for (int rt = 0; rt < 2; ++rt)
#pragma unroll
    for (int t = 0; t < 4; ++t) {
      f32x4 e0 = accS[rt][2 * t], e1 = accS[rt][2 * t + 1];
      bf16x8 f;
      f[0] = f2bf(e0[0]); f[1] = f2bf(e0[1]); f[2] = f2bf(e0[2]); f[3] = f2bf(e0[3]);
      f[4] = f2bf(e1[0]); f[5] = f2bf(e1[1]); f[6] = f2bf(e1[2]); f[7] = f2bf(e1[3]);
      pb[rt][t] = f;
    }

  // --- Phase 3: O^T partial = mem^T . P^T over wave's f-slice ---
  f32x4 accO[8][2];
#pragma unroll
  for (int dt = 0; dt < 8; ++dt) {
    f32x4 o0 = {0.f, 0.f, 0.f, 0.f}, o1 = {0.f, 0.f, 0.f, 0.f};
    const short* mT = memTb + (size_t)(dt * 16 + lr) * MM + w * 128;
#pragma unroll
    for (int t = 0; t < 4; ++t) {
      bf16x8 af = ldfrag(mT + t * 32 + lg * 4);
      o0 = __builtin_amdgcn_mfma_f32_16x16x32_bf16(af, pb[0][t], o0, 0, 0, 0);
      o1 = __builtin_amdgcn_mfma_f32_16x16x32_bf16(af, pb[1][t], o1, 0, 0, 0);
    }
    accO[dt][0] = o0;
    accO[dt][1] = o1;
  }

  // --- Phase 4: pairwise cross-wave reduction ---
  if (w >= 2) {
#pragma unroll
    for (int dt = 0; dt < 8; ++dt)
#pragma unroll
      for (int rt = 0; rt < 2; ++rt) {
        f32x4 o = accO[dt][rt];
        *(float4*)&opart[w - 2][(lr + 16 * rt) * 132 + dt * 16 + lg * 4] =
            make_float4(o[0], o[1], o[2], o[3]);
      }
  }
  __syncthreads();
  if (w < 2) {
#pragma unroll
    for (int dt = 0; dt < 8; ++dt)
#pragma unroll
      for (int rt = 0; rt < 2; ++rt) {
        float* p = &opart[w][(lr + 16 * rt) * 132 + dt * 16 + lg * 4];
        float4 q = *(const float4*)p;
        f32x4 o = accO[dt][rt];
        *(float4*)p = make_float4(o[0] + q.x, o[1] + q.y, o[2] + q.z, o[3] + q.w);
      }
  }
  __syncthreads();

  // --- normalize + store O to r2[:,0..127] (fp32) ---
#pragma unroll
  for (int i = 0; i < 4; ++i) {
    int pos = tid + i * 256;
    int r = pos >> 5, s4 = (pos & 31) * 4;
    float inv = 1.f / (((psum_lds[0][r] + psum_lds[1][r]) + psum_lds[2][r]) +
                       psum_lds[3][r]);
    float4 a = *(const float4*)&opart[0][r * 132 + s4];
    float4 b = *(const float4*)&opart[1][r * 132 + s4];
    *(float4*)&r2[(size_t)(n0 + r) * 256 + s4] =
        make_float4((a.x + b.x) * inv, (a.y + b.y) * inv, (a.z + b.z) * inv,
                    (a.w + b.w) * inv);
  }
}

// ---------------------------------------------------------------------------
// Kernel 4: fused dual-branch GEMM2 + bias + add + transposed store.
// ---------------------------------------------------------------------------
__global__ __launch_bounds__(256) void gemm2_kernel(
    const float* __restrict__ r2s, const float* __restrict__ r2t,
    const float* __restrict__ Ws2, const float* __restrict__ Wt2,
    const float* __restrict__ bs2, const float* __restrict__ bt2,
    float* __restrict__ out) {
  int b = blockIdx.z;
  int c0 = blockIdx.x * 64;
  int p0 = blockIdx.y * 64;
  __shared__ float As[16][68];
  __shared__ float At[16][68];
  __shared__ float Bs[16][68];
  __shared__ float Bt[16][68];
  int tid = threadIdx.x;
  int tx = tid & 15, ty = tid >> 4;
  int lr = tid >> 2;
  int lk = (tid & 3) * 4;
  float acc[4][4] = {{0.f}};

  for (int k0 = 0; k0 < 256; k0 += 16) {
    {
      int c = c0 + lr;
      float4 a4s = make_float4(0, 0, 0, 0), a4t = a4s;
      if (c < CC) {
        size_t base = ((size_t)b * CC + c) * 256 + k0 + lk;
        a4s = *(const float4*)(r2s + base);
        a4t = *(const float4*)(r2t + base);
      }
      As[lk + 0][lr] = a4s.x; As[lk + 1][lr] = a4s.y;
      As[lk + 2][lr] = a4s.z; As[lk + 3][lr] = a4s.w;
      At[lk + 0][lr] = a4t.x; At[lk + 1][lr] = a4t.y;
      At[lk + 2][lr] = a4t.z; At[lk + 3][lr] = a4t.w;
      int p = p0 + lr;
      float4 b4s = make_float4(0, 0, 0, 0), b4t = b4s;
      if (p < PP) {
        size_t base = (size_t)p * 256 + k0 + lk;
        b4s = *(const float4*)(Ws2 + base);
        b4t = *(const float4*)(Wt2 + base);
      }
      Bs[lk + 0][lr] = b4s.x; Bs[lk + 1][lr] = b4s.y;
      Bs[lk + 2][lr] = b4s.z; Bs[lk + 3][lr] = b4s.w;
      Bt[lk + 0][lr] = b4t.x; Bt[lk + 1][lr] = b4t.y;
      Bt[lk + 2][lr] = b4t.z; Bt[lk + 3][lr] = b4t.w;
    }
    __syncthreads();
#pragma unroll
    for (int k = 0; k < 16; ++k) {
      float4 as4 = *(const float4*)&As[k][tx * 4];
      float4 at4 = *(const float4*)&At[k][tx * 4];
      float4 bs4 = *(const float4*)&Bs[k][ty * 4];
      float4 bt4 = *(const float4*)&Bt[k][ty * 4];
      float av_s[4] = {as4.x, as4.y, as4.z, as4.w};
      float av_t[4] = {at4.x, at4.y, at4.z, at4.w};
      float bv_s[4] = {bs4.x, bs4.y, bs4.z, bs4.w};
      float bv_t[4] = {bt4.x, bt4.y, bt4.z, bt4.w};
#pragma unroll
      for (int i = 0; i < 4; ++i)
#pragma unroll
        for (int j = 0; j < 4; ++j) {
          acc[i][j] = fmaf(av_s[i], bv_s[j], acc[i][j]);
          acc[i][j] = fmaf(av_t[i], bv_t[j], acc[i][j]);
        }
    }
    __syncthreads();
  }

#pragma unroll
  for (int j = 0; j < 4; ++j) {
    int p = p0 + ty * 4 + j;
    if (p >= PP) continue;
    float bias = bs2[p] + bt2[p];
    size_t rowbase = ((size_t)b * PP + p) * CC;
#pragma unroll
    for (int i = 0; i < 4; ++i) {
      int c = c0 + tx * 4 + i;
      if (c < CC) out[rowbase + c] = acc[i][j] + bias;
    }
  }
}

// ---------------------------------------------------------------------------
extern "C" void kernel_launch(void* const* d_in, const int* in_sizes, int n_in,
                              void* d_out, int out_size, void* d_ws, size_t ws_size,
                              hipStream_t stream) {
  const float* x    = (const float*)d_in[0];
  const float* Ws1  = (const float*)d_in[1];
  const float* bs1  = (const float*)d_in[2];
  const float* Ws2  = (const float*)d_in[3];
  const float* bs2  = (const float*)d_in[4];
  const float* Wt1  = (const float*)d_in[5];
  const float* bt1  = (const float*)d_in[6];
  const float* Wt2  = (const float*)d_in[7];
  const float* bt2  = (const float*)d_in[8];
  const float* memS = (const float*)d_in[9];
  const float* memT = (const float*)d_in[10];
  float* out = (float*)d_out;

  const size_t N = (size_t)BB * CC;          // 41088
  float* ws    = (float*)d_ws;
  float* r2s   = ws;                         // [N,256] fp32
  float* r2t   = r2s + N * 256;              // [N,256] fp32
  short* WsTb  = (short*)(r2t + N * 256);    // [H][LPAD] bf16
  short* WtTb  = WsTb + (size_t)HH * LPAD;
  short* mSb   = WtTb + (size_t)HH * LPAD;   // [512][128] bf16
  short* mSTb  = mSb + (size_t)MM * HH;      // [128][512] bf16
  short* mTb   = mSTb + (size_t)MM * HH;
  short* mTTb  = mTb + (size_t)MM * HH;
  // total ~= 84.1 MB + 0.9 MB

  // 1. smeared weights -> bf16 [H][LPAD]
  weff_kernel<<<(HH * LPAD + 255) / 256, 256, 0, stream>>>(Ws1, Wt1, WsTb, WtTb);

  // 1b. mem -> bf16 (natural + transposed)
  memcvt_kernel<<<(MM * HH + 255) / 256, 256, 0, stream>>>(memS, memT, mSb, mSTb,
                                                           mTb, mTTb);

  // 2. MFMA GEMM1 + sigmoid (both branches)
  dim3 g1((CC + 63) / 64, BB);
  gemm1_mfma<<<g1, 256, 0, stream>>>(x, WsTb, WtTb, bs1, bt1, r2s, r2t);

  // 3. MFMA memory enhance per branch (N/32 = 1284 blocks)
  int nblk = (int)(N / 32);
  memenh_mfma<<<nblk, 256, 0, stream>>>(mSb, mSTb, r2s);
  memenh_mfma<<<nblk, 256, 0, stream>>>(mTb, mTTb, r2t);

  // 4. GEMM2 + bias + add + transpose-store
  dim3 g2((CC + 63) / 64, (PP + 63) / 64, BB);
  gemm2_kernel<<<g2, 256, 0, stream>>>(r2s, r2t, Ws2, Wt2, bs2, bt2, out);
}

// Round 4
// 395.423 us; speedup vs baseline: 4.1532x; 1.7824x over previous
//
#include <hip/hip_runtime.h>
#include <math.h>

#define BB 128
#define LL 720
#define CC 321
#define HH 128
#define PP 336
#define MM 512
#define LPAD 736  // 720 padded to multiple of 32

typedef __attribute__((ext_vector_type(8))) short bf16x8;
typedef __attribute__((ext_vector_type(4))) float f32x4;

__device__ __forceinline__ short f2bf(float x) {
  unsigned u = __builtin_bit_cast(unsigned, x);
  u = (u + 0x7FFFu + ((u >> 16) & 1u)) >> 16;
  return (short)u;
}

// load an 8-element bf16 MFMA fragment from global: elems 0..3 at p, 4..7 at p+16
__device__ __forceinline__ bf16x8 ldfrag(const short* p) {
  short4 a = *(const short4*)p;
  short4 b = *(const short4*)(p + 16);
  bf16x8 r;
  r[0] = a.x; r[1] = a.y; r[2] = a.z; r[3] = a.w;
  r[4] = b.x; r[5] = b.y; r[6] = b.z; r[7] = b.w;
  return r;
}

// async global->LDS, 16 bytes per lane
__device__ __forceinline__ void gload_lds16(const short* g, short* l) {
  __builtin_amdgcn_global_load_lds(
      (const __attribute__((address_space(1))) unsigned int*)g,
      (__attribute__((address_space(3))) unsigned int*)l, 16, 0, 0);
}

// Read an A-frag from a 64B-row LDS tile (rows=16*tiles, 32 bf16 k each),
// stored with chunk-XOR swizzle: lds[h][q] holds global chunk q^(h&3).
__device__ __forceinline__ bf16x8 ldsfrag(const short* tile, int h, int lg) {
  int base = h * 32;
  int off = (lg & 1) * 4;
  int g1 = ((lg >> 1) ^ (h & 3)) * 8;
  int g2 = (((lg >> 1) + 2) ^ (h & 3)) * 8;
  short4 a = *(const short4*)&tile[base + g1 + off];
  short4 b = *(const short4*)&tile[base + g2 + off];
  bf16x8 r;
  r[0] = a.x; r[1] = a.y; r[2] = a.z; r[3] = a.w;
  r[4] = b.x; r[5] = b.y; r[6] = b.z; r[7] = b.w;
  return r;
}

// ---------------------------------------------------------------------------
// Kernel 1: effective (smeared) weights -> bf16 [H][LPAD] (zero-padded tail).
// ---------------------------------------------------------------------------
__global__ void weff_kernel(const float* __restrict__ Ws1,
                            const float* __restrict__ Wt1,
                            short* __restrict__ WsT,
                            short* __restrict__ WtT) {
  int idx = blockIdx.x * 256 + threadIdx.x;
  if (idx >= HH * LPAD) return;
  int j = idx % LPAD, h = idx / LPAD;
  if (j >= LL) { WsT[idx] = 0; WtT[idx] = 0; return; }
  float ss = 0.f, st = 0.f;
  if (j == 0) {
    for (int l = 0; l <= 12; ++l) {
      float w = 13.f - (float)l;
      ss += w * Ws1[h * LL + l];
      st += w * Wt1[h * LL + l];
    }
  } else if (j == LL - 1) {
    for (int d = 0; d <= 12; ++d) {
      float w = 13.f - (float)d;
      ss += w * Ws1[h * LL + LL - 1 - d];
      st += w * Wt1[h * LL + LL - 1 - d];
    }
  } else {
    int lo = j - 12 < 0 ? 0 : j - 12;
    int hi = j + 12 > LL - 1 ? LL - 1 : j + 12;
    for (int l = lo; l <= hi; ++l) {
      ss += Ws1[h * LL + l];
      st += Wt1[h * LL + l];
    }
  }
  ss *= (1.f / 25.f);
  st *= (1.f / 25.f);
  WsT[idx] = f2bf(Ws1[h * LL + j] - ss);
  WtT[idx] = f2bf(st);
}

// ---------------------------------------------------------------------------
// Kernel 1b: mem -> bf16 natural + transposed.
// ---------------------------------------------------------------------------
__global__ void memcvt_kernel(const float* __restrict__ memS,
                              const float* __restrict__ memT,
                              short* __restrict__ mSb, short* __restrict__ mSTb,
                              short* __restrict__ mTb, short* __restrict__ mTTb) {
  int i = blockIdx.x * 256 + threadIdx.x;
  if (i >= MM * HH) return;
  int f = i >> 7, d = i & 127;
  short vs = f2bf(memS[i]);
  short vt = f2bf(memT[i]);
  mSb[i] = vs;
  mSTb[d * MM + f] = vs;
  mTb[i] = vt;
  mTTb[d * MM + f] = vt;
}

// ---------------------------------------------------------------------------
// Kernel 1c: W2cat bf16 [336][512] (k<256 = seasonal, else trend) + bias sum.
// ---------------------------------------------------------------------------
__global__ void w2cvt_kernel(const float* __restrict__ Ws2,
                             const float* __restrict__ Wt2,
                             const float* __restrict__ bs2,
                             const float* __restrict__ bt2,
                             short* __restrict__ W2b, float* __restrict__ b2) {
  int i = blockIdx.x * 256 + threadIdx.x;
  if (i < PP) b2[i] = bs2[i] + bt2[i];
  if (i >= PP * 512) return;
  int p = i >> 9, k = i & 511;
  float v = (k < 256) ? Ws2[p * 256 + k] : Wt2[p * 256 + (k - 256)];
  W2b[i] = f2bf(v);
}

// ---------------------------------------------------------------------------
// Kernel 2: MFMA dual-branch GEMM1 + sigmoid, LDS-staged + double-buffered.
//   512 thr / 8 waves; block = 128 n x 128 h x 2 branches; BK=32.
//   W tiles staged via global_load_lds (16B/lane) with chunk-XOR swizzle;
//   x gathered per-lane into B-frags (read exactly once overall).
//   Output: bf16 R at r2[n][128..255] (shorts).
// ---------------------------------------------------------------------------
__global__ __launch_bounds__(512) void gemm1_mfma(
    const float* __restrict__ x,
    const short* __restrict__ WsT, const short* __restrict__ WtT,
    const float* __restrict__ bs1, const float* __restrict__ bt1,
    short* __restrict__ r2s, short* __restrict__ r2t) {
  __shared__ __align__(16) short wlds[2][2][4096];  // [buf][branch][128h*32k]
  int tid = threadIdx.x;
  int w = tid >> 6, l = tid & 63, lr = l & 15, lg = l >> 4;
  int n = blockIdx.x * 128 + w * 16 + lr;  // 41088 = 321*128 exact
  int b = n / CC;
  int c = n - b * CC;
  const float* xb = x + (size_t)b * (LL * CC) + c;

  // staging lanes: row sh, 16B chunk sq; source pre-swizzled (m173 pattern)
  int sh = tid >> 2, sq = tid & 3;
  const short* srcS = WsT + sh * LPAD + (sq ^ (sh & 3)) * 8;
  const short* srcT = WtT + sh * LPAD + (sq ^ (sh & 3)) * 8;

  f32x4 acc[2][8];
#pragma unroll
  for (int br = 0; br < 2; ++br)
#pragma unroll
    for (int i = 0; i < 8; ++i) acc[br][i] = (f32x4){0.f, 0.f, 0.f, 0.f};

  gload_lds16(srcS, &wlds[0][0][tid * 8]);
  gload_lds16(srcT, &wlds[0][1][tid * 8]);
  __syncthreads();

  int cur = 0;
  for (int step = 0; step < 23; ++step) {
    if (step < 22) {
      int k0n = (step + 1) * 32;
      gload_lds16(srcS + k0n, &wlds[cur ^ 1][0][tid * 8]);
      gload_lds16(srcT + k0n, &wlds[cur ^ 1][1][tid * 8]);
    }
    int k0 = step * 32;
    bf16x8 bx;
#pragma unroll
    for (int j = 0; j < 4; ++j) {
      int k1 = k0 + lg * 4 + j;       // always < 720
      int k2 = k1 + 16;               // >= 720 only at step 22
      float v1 = xb[(size_t)k1 * CC];
      float v2 = (k2 < LL) ? xb[(size_t)k2 * CC] : 0.f;
      bx[j] = f2bf(v1);
      bx[j + 4] = f2bf(v2);
    }
    const short* tS = &wlds[cur][0][0];
    const short* tT = &wlds[cur][1][0];
#pragma unroll
    for (int ht = 0; ht < 8; ++ht) {
      bf16x8 aS = ldsfrag(tS, ht * 16 + lr, lg);
      bf16x8 aT = ldsfrag(tT, ht * 16 + lr, lg);
      acc[0][ht] =
          __builtin_amdgcn_mfma_f32_16x16x32_bf16(aS, bx, acc[0][ht], 0, 0, 0);
      acc[1][ht] =
          __builtin_amdgcn_mfma_f32_16x16x32_bf16(aT, bx, acc[1][ht], 0, 0, 0);
    }
    __syncthreads();
    cur ^= 1;
  }

  // epilogue: sigmoid -> bf16 R at shorts [128..255] of each r2 row
  short* rowS = r2s + (size_t)n * 256 + 128;
  short* rowT = r2t + (size_t)n * 256 + 128;
#pragma unroll
  for (int ht = 0; ht < 8; ++ht) {
    int h = ht * 16 + lg * 4;  // D row = (lane>>4)*4 + reg, tile ht
    float4 bS = *(const float4*)&bs1[h];
    float4 bT = *(const float4*)&bt1[h];
    const float* pbS = &bS.x;
    const float* pbT = &bT.x;
    short4 ss, st;
    short* ps = &ss.x;
    short* pt = &st.x;
#pragma unroll
    for (int j = 0; j < 4; ++j) {
      ps[j] = f2bf(1.f / (1.f + __expf(-(acc[0][ht][j] + pbS[j]))));
      pt[j] = f2bf(1.f / (1.f + __expf(-(acc[1][ht][j] + pbT[j]))));
    }
    *(short4*)&rowS[h] = ss;
    *(short4*)&rowT[h] = st;
  }
}

// ---------------------------------------------------------------------------
// Kernel 3: MFMA memory-enhance. 32 rows/block, 4 waves.
//   Reads bf16 R from r2[n][128..255]; writes bf16 O to r2[n][0..127].
// ---------------------------------------------------------------------------
__global__ __launch_bounds__(256) void memenh_mfma(
    const short* __restrict__ memb,   // [512][128] bf16
    const short* __restrict__ memTb,  // [128][512] bf16
    short* __restrict__ r2) {
  int n0 = blockIdx.x * 32;
  int tid = threadIdx.x;
  int w = tid >> 6;
  int l = tid & 63;
  int lr = l & 15;
  int lg = l >> 4;

  __shared__ float pmax_lds[4][32];
  __shared__ float psum_lds[4][32];
  __shared__ float opart[2][32 * 132];

  // --- B-frags: R rows ---
  bf16x8 brag[2][4];
#pragma unroll
  for (int rt = 0; rt < 2; ++rt) {
    const short* rb = r2 + (size_t)(n0 + lr + 16 * rt) * 256 + 128;
#pragma unroll
    for (int k = 0; k < 4; ++k) brag[rt][k] = ldfrag(rb + k * 32 + lg * 4);
  }

  // --- Phase 1: S^T = mem . R^T ---
  f32x4 accS[2][8];
#pragma unroll
  for (int ft = 0; ft < 8; ++ft) {
    f32x4 a0 = {0.f, 0.f, 0.f, 0.f}, a1 = {0.f, 0.f, 0.f, 0.f};
    const short* mrow = memb + (size_t)(w * 128 + ft * 16 + lr) * 128;
#pragma unroll
    for (int k = 0; k < 4; ++k) {
      bf16x8 af = ldfrag(mrow + k * 32 + lg * 4);
      a0 = __builtin_amdgcn_mfma_f32_16x16x32_bf16(af, brag[0][k], a0, 0, 0, 0);
      a1 = __builtin_amdgcn_mfma_f32_16x16x32_bf16(af, brag[1][k], a1, 0, 0, 0);
    }
    accS[0][ft] = a0;
    accS[1][ft] = a1;
  }

  // --- Phase 2: softmax along f ---
#pragma unroll
  for (int rt = 0; rt < 2; ++rt) {
    float mx = -3.4e38f;
#pragma unroll
    for (int ft = 0; ft < 8; ++ft) {
      f32x4 v = accS[rt][ft];
      mx = fmaxf(mx, fmaxf(fmaxf(v[0], v[1]), fmaxf(v[2], v[3])));
    }
    mx = fmaxf(mx, __shfl_xor(mx, 16));
    mx = fmaxf(mx, __shfl_xor(mx, 32));
    if (lg == 0) pmax_lds[w][rt * 16 + lr] = mx;
  }
  __syncthreads();
#pragma unroll
  for (int rt = 0; rt < 2; ++rt) {
    float gm = fmaxf(fmaxf(pmax_lds[0][rt * 16 + lr], pmax_lds[1][rt * 16 + lr]),
                     fmaxf(pmax_lds[2][rt * 16 + lr], pmax_lds[3][rt * 16 + lr]));
    float s = 0.f;
#pragma unroll
    for (int ft = 0; ft < 8; ++ft) {
      f32x4 v = accS[rt][ft];
#pragma unroll
      for (int j = 0; j < 4; ++j) {
        float e = __expf(v[j] - gm);
        v[j] = e;
        s += e;
      }
      accS[rt][ft] = v;
    }
    s += __shfl_xor(s, 16);
    s += __shfl_xor(s, 32);
    if (lg == 0) psum_lds[w][rt * 16 + lr] = s;
  }

  // --- P^T -> bf16 PV B-frags ---
  bf16x8 pb[2][4];
#pragma unroll
  for (int rt = 0; rt < 2; ++rt)
#pragma unroll
    for (int t = 0; t < 4; ++t) {
      f32x4 e0 = accS[rt][2 * t], e1 = accS[rt][2 * t + 1];
      bf16x8 f;
      f[0] = f2bf(e0[0]); f[1] = f2bf(e0[1]); f[2] = f2bf(e0[2]); f[3] = f2bf(e0[3]);
      f[4] = f2bf(e1[0]); f[5] = f2bf(e1[1]); f[6] = f2bf(e1[2]); f[7] = f2bf(e1[3]);
      pb[rt][t] = f;
    }

  // --- Phase 3: O^T partial = mem^T . P^T ---
  f32x4 accO[8][2];
#pragma unroll
  for (int dt = 0; dt < 8; ++dt) {
    f32x4 o0 = {0.f, 0.f, 0.f, 0.f}, o1 = {0.f, 0.f, 0.f, 0.f};
    const short* mT = memTb + (size_t)(dt * 16 + lr) * MM + w * 128;
#pragma unroll
    for (int t = 0; t < 4; ++t) {
      bf16x8 af = ldfrag(mT + t * 32 + lg * 4);
      o0 = __builtin_amdgcn_mfma_f32_16x16x32_bf16(af, pb[0][t], o0, 0, 0, 0);
      o1 = __builtin_amdgcn_mfma_f32_16x16x32_bf16(af, pb[1][t], o1, 0, 0, 0);
    }
    accO[dt][0] = o0;
    accO[dt][1] = o1;
  }

  // --- Phase 4: cross-wave reduction ---
  if (w >= 2) {
#pragma unroll
    for (int dt = 0; dt < 8; ++dt)
#pragma unroll
      for (int rt = 0; rt < 2; ++rt) {
        f32x4 o = accO[dt][rt];
        *(float4*)&opart[w - 2][(lr + 16 * rt) * 132 + dt * 16 + lg * 4] =
            make_float4(o[0], o[1], o[2], o[3]);
      }
  }
  __syncthreads();
  if (w < 2) {
#pragma unroll
    for (int dt = 0; dt < 8; ++dt)
#pragma unroll
      for (int rt = 0; rt < 2; ++rt) {
        float* p = &opart[w][(lr + 16 * rt) * 132 + dt * 16 + lg * 4];
        float4 q = *(const float4*)p;
        f32x4 o = accO[dt][rt];
        *(float4*)p = make_float4(o[0] + q.x, o[1] + q.y, o[2] + q.z, o[3] + q.w);
      }
  }
  __syncthreads();

  // --- normalize + store O as bf16 to r2[:,0..127] shorts ---
#pragma unroll
  for (int i = 0; i < 2; ++i) {
    int pos = tid + i * 256;          // 0..511
    int r = pos >> 4, d0 = (pos & 15) * 8;
    float inv = 1.f / (((psum_lds[0][r] + psum_lds[1][r]) + psum_lds[2][r]) +
                       psum_lds[3][r]);
    float4 a0 = *(const float4*)&opart[0][r * 132 + d0];
    float4 a1 = *(const float4*)&opart[0][r * 132 + d0 + 4];
    float4 b0 = *(const float4*)&opart[1][r * 132 + d0];
    float4 b1 = *(const float4*)&opart[1][r * 132 + d0 + 4];
    bf16x8 o;
    o[0] = f2bf((a0.x + b0.x) * inv);
    o[1] = f2bf((a0.y + b0.y) * inv);
    o[2] = f2bf((a0.z + b0.z) * inv);
    o[3] = f2bf((a0.w + b0.w) * inv);
    o[4] = f2bf((a1.x + b1.x) * inv);
    o[5] = f2bf((a1.y + b1.y) * inv);
    o[6] = f2bf((a1.z + b1.z) * inv);
    o[7] = f2bf((a1.w + b1.w) * inv);
    *(bf16x8*)&r2[(size_t)(n0 + r) * 256 + d0] = o;
  }
}

// ---------------------------------------------------------------------------
// Kernel 4: MFMA GEMM2 (bf16, K=512 concat) + bias + transposed store.
//   512 thr / 8 waves; block = 128 n x 112 p; grid (321, 3).
//   D[p][n] orientation makes the [b,p,c] store natural.
// ---------------------------------------------------------------------------
__global__ __launch_bounds__(512) void gemm2_mfma(
    const short* __restrict__ r2s, const short* __restrict__ r2t,
    const short* __restrict__ W2b,  // [336][512] bf16
    const float* __restrict__ b2,   // [336]
    float* __restrict__ out) {
  __shared__ __align__(16) short w2lds[2][3584];  // 112 rows * 32 k
  int tid = threadIdx.x;
  int w = tid >> 6, l = tid & 63, lr = l & 15, lg = l >> 4;
  int p0 = blockIdx.y * 112;
  int n = blockIdx.x * 128 + w * 16 + lr;
  int b = n / CC, c = n - b * CC;
  const short* rs = r2s + (size_t)n * 256;
  const short* rt = r2t + (size_t)n * 256;

  int sh = tid >> 2, sq = tid & 3;
  const short* srcW = W2b + (size_t)(p0 + sh) * 512 + (sq ^ (sh & 3)) * 8;
  bool dostage = tid < 448;  // waves 0..6 stage (448 = 112 rows * 4 chunks)

  f32x4 acc[7];
#pragma unroll
  for (int i = 0; i < 7; ++i) acc[i] = (f32x4){0.f, 0.f, 0.f, 0.f};

  if (dostage) gload_lds16(srcW, &w2lds[0][tid * 8]);
  __syncthreads();

  int cur = 0;
  for (int step = 0; step < 16; ++step) {
    if (step < 15 && dostage)
      gload_lds16(srcW + (step + 1) * 32, &w2lds[cur ^ 1][tid * 8]);
    int k0 = step * 32;
    const short* rrow = ((k0 < 256) ? rs : rt) + (k0 & 255);
    bf16x8 bfr = ldfrag(rrow + lg * 4);
    const short* tw = &w2lds[cur][0];
#pragma unroll
    for (int pt = 0; pt < 7; ++pt) {
      bf16x8 a = ldsfrag(tw, pt * 16 + lr, lg);
      acc[pt] = __builtin_amdgcn_mfma_f32_16x16x32_bf16(a, bfr, acc[pt], 0, 0, 0);
    }
    __syncthreads();
    cur ^= 1;
  }

  size_t obase = (size_t)b * ((size_t)PP * CC) + c;
#pragma unroll
  for (int pt = 0; pt < 7; ++pt) {
    int p = p0 + pt * 16 + lg * 4;
    float4 bias = *(const float4*)&b2[p];
    const float* pb = &bias.x;
#pragma unroll
    for (int j = 0; j < 4; ++j) {
      out[obase + (size_t)(p + j) * CC] = acc[pt][j] + pb[j];
    }
  }
}

// ---------------------------------------------------------------------------
extern "C" void kernel_launch(void* const* d_in, const int* in_sizes, int n_in,
                              void* d_out, int out_size, void* d_ws, size_t ws_size,
                              hipStream_t stream) {
  const float* x    = (const float*)d_in[0];
  const float* Ws1  = (const float*)d_in[1];
  const float* bs1  = (const float*)d_in[2];
  const float* Ws2  = (const float*)d_in[3];
  const float* bs2  = (const float*)d_in[4];
  const float* Wt1  = (const float*)d_in[5];
  const float* bt1  = (const float*)d_in[6];
  const float* Wt2  = (const float*)d_in[7];
  const float* bt2  = (const float*)d_in[8];
  const float* memS = (const float*)d_in[9];
  const float* memT = (const float*)d_in[10];
  float* out = (float*)d_out;

  const size_t N = (size_t)BB * CC;          // 41088
  short* r2s  = (short*)d_ws;                // [N][256] bf16: [O | R]
  short* r2t  = r2s + N * 256;
  short* WsTb = r2t + N * 256;               // [H][LPAD] bf16
  short* WtTb = WsTb + (size_t)HH * LPAD;
  short* mSb  = WtTb + (size_t)HH * LPAD;    // [512][128] bf16
  short* mSTb = mSb + (size_t)MM * HH;       // [128][512]
  short* mTb  = mSTb + (size_t)MM * HH;
  short* mTTb = mTb + (size_t)MM * HH;
  short* W2b  = mTTb + (size_t)MM * HH;      // [336][512] bf16
  float* b2   = (float*)(W2b + (size_t)PP * 512);
  // total ~= 43 MB

  // 1. precompute weights / conversions
  weff_kernel<<<(HH * LPAD) / 256, 256, 0, stream>>>(Ws1, Wt1, WsTb, WtTb);
  memcvt_kernel<<<(MM * HH) / 256, 256, 0, stream>>>(memS, memT, mSb, mSTb,
                                                     mTb, mTTb);
  w2cvt_kernel<<<(PP * 512) / 256, 256, 0, stream>>>(Ws2, Wt2, bs2, bt2, W2b, b2);

  // 2. MFMA GEMM1 + sigmoid (both branches)
  gemm1_mfma<<<321, 512, 0, stream>>>(x, WsTb, WtTb, bs1, bt1, r2s, r2t);

  // 3. MFMA memory enhance per branch
  int nblk = (int)(N / 32);  // 1284
  memenh_mfma<<<nblk, 256, 0, stream>>>(mSb, mSTb, r2s);
  memenh_mfma<<<nblk, 256, 0, stream>>>(mTb, mTTb, r2t);

  // 4. MFMA GEMM2 + bias + transposed store
  dim3 g2(321, 3);
  gemm2_mfma<<<g2, 512, 0, stream>>>(r2s, r2t, W2b, b2, out);
}

// Round 5
// 299.401 us; speedup vs baseline: 5.4852x; 1.3207x over previous
//
#include <hip/hip_runtime.h>
#include <math.h>

#define BB 128
#define LL 720
#define CC 321
#define HH 128
#define PP 336
#define MM 512
#define LPAD 736  // 720 padded to multiple of 32

typedef __attribute__((ext_vector_type(8))) short bf16x8;
typedef __attribute__((ext_vector_type(4))) float f32x4;

__device__ __forceinline__ short f2bf(float x) {
  unsigned u = __builtin_bit_cast(unsigned, x);
  u = (u + 0x7FFFu + ((u >> 16) & 1u)) >> 16;
  return (short)u;
}

// load an 8-element bf16 MFMA fragment from global: elems 0..3 at p, 4..7 at p+16
__device__ __forceinline__ bf16x8 ldfrag(const short* p) {
  short4 a = *(const short4*)p;
  short4 b = *(const short4*)(p + 16);
  bf16x8 r;
  r[0] = a.x; r[1] = a.y; r[2] = a.z; r[3] = a.w;
  r[4] = b.x; r[5] = b.y; r[6] = b.z; r[7] = b.w;
  return r;
}

// Stage one 16B "fragment chunk" from global W row: 8B at g, 8B at g+16.
// (permutes the two k-halves adjacent so LDS holds ready-to-read fragments)
__device__ __forceinline__ int4 stage_chunk(const short* g) {
  int2 lo = *(const int2*)g;
  int2 hi = *(const int2*)(g + 16);
  int4 r;
  r.x = lo.x; r.y = lo.y; r.z = hi.x; r.w = hi.y;
  return r;
}

// Fragment read from padded LDS tile: rows of 40 shorts (80 B), fragment for
// (row h, lane-group lg) is 8 contiguous shorts at h*40 + lg*8 -> ds_read_b128.
__device__ __forceinline__ bf16x8 ldsfragP(const short* tile, int h, int lg) {
  return *(const bf16x8*)&tile[h * 40 + lg * 8];
}

// ---------------------------------------------------------------------------
// Kernel 1: effective (smeared) weights -> bf16 [H][LPAD] (zero-padded tail).
// ---------------------------------------------------------------------------
__global__ void weff_kernel(const float* __restrict__ Ws1,
                            const float* __restrict__ Wt1,
                            short* __restrict__ WsT,
                            short* __restrict__ WtT) {
  int idx = blockIdx.x * 256 + threadIdx.x;
  if (idx >= HH * LPAD) return;
  int j = idx % LPAD, h = idx / LPAD;
  if (j >= LL) { WsT[idx] = 0; WtT[idx] = 0; return; }
  float ss = 0.f, st = 0.f;
  if (j == 0) {
    for (int l = 0; l <= 12; ++l) {
      float w = 13.f - (float)l;
      ss += w * Ws1[h * LL + l];
      st += w * Wt1[h * LL + l];
    }
  } else if (j == LL - 1) {
    for (int d = 0; d <= 12; ++d) {
      float w = 13.f - (float)d;
      ss += w * Ws1[h * LL + LL - 1 - d];
      st += w * Wt1[h * LL + LL - 1 - d];
    }
  } else {
    int lo = j - 12 < 0 ? 0 : j - 12;
    int hi = j + 12 > LL - 1 ? LL - 1 : j + 12;
    for (int l = lo; l <= hi; ++l) {
      ss += Ws1[h * LL + l];
      st += Wt1[h * LL + l];
    }
  }
  ss *= (1.f / 25.f);
  st *= (1.f / 25.f);
  WsT[idx] = f2bf(Ws1[h * LL + j] - ss);
  WtT[idx] = f2bf(st);
}

// ---------------------------------------------------------------------------
// Kernel 1b: mem -> bf16 natural + transposed.
// ---------------------------------------------------------------------------
__global__ void memcvt_kernel(const float* __restrict__ memS,
                              const float* __restrict__ memT,
                              short* __restrict__ mSb, short* __restrict__ mSTb,
                              short* __restrict__ mTb, short* __restrict__ mTTb) {
  int i = blockIdx.x * 256 + threadIdx.x;
  if (i >= MM * HH) return;
  int f = i >> 7, d = i & 127;
  short vs = f2bf(memS[i]);
  short vt = f2bf(memT[i]);
  mSb[i] = vs;
  mSTb[d * MM + f] = vs;
  mTb[i] = vt;
  mTTb[d * MM + f] = vt;
}

// ---------------------------------------------------------------------------
// Kernel 1c: W2cat bf16 [336][512] (k<256 = seasonal, else trend) + bias sum.
// ---------------------------------------------------------------------------
__global__ void w2cvt_kernel(const float* __restrict__ Ws2,
                             const float* __restrict__ Wt2,
                             const float* __restrict__ bs2,
                             const float* __restrict__ bt2,
                             short* __restrict__ W2b, float* __restrict__ b2) {
  int i = blockIdx.x * 256 + threadIdx.x;
  if (i < PP) b2[i] = bs2[i] + bt2[i];
  if (i >= PP * 512) return;
  int p = i >> 9, k = i & 511;
  float v = (k < 256) ? Ws2[p * 256 + k] : Wt2[p * 256 + (k - 256)];
  W2b[i] = f2bf(v);
}

// ---------------------------------------------------------------------------
// Kernel 2: MFMA dual-branch GEMM1 + sigmoid.
//   256 thr / 4 waves; block = 64 n x 128 h x 2 branches; BK=32; grid 642.
//   W reg-staged into padded 80B-row LDS (fragment-contiguous, ds_read_b128,
//   conflict-minimal); double-buffered; x gathered per-lane, pipelined 1 step.
// ---------------------------------------------------------------------------
__global__ __launch_bounds__(256) void gemm1_mfma(
    const float* __restrict__ x,
    const short* __restrict__ WsT, const short* __restrict__ WtT,
    const float* __restrict__ bs1, const float* __restrict__ bt1,
    short* __restrict__ r2s, short* __restrict__ r2t) {
  __shared__ __align__(16) short wlds[2][2][128 * 40];  // 40 KB
  int tid = threadIdx.x;
  int w = tid >> 6, l = tid & 63, lr = l & 15, lg = l >> 4;
  int n = blockIdx.x * 64 + w * 16 + lr;  // 41088 = 642*64 exact
  int b = n / CC;
  int c = n - b * CC;
  const float* xb = x + (size_t)b * (LL * CC) + c;

  // staging: thread handles chunks e=tid (row0,q) and e=tid+256 (row0+64,q)
  int row0 = tid >> 2, q = tid & 3;
  const short* gS0 = WsT + row0 * LPAD + q * 4;
  const short* gS1 = gS0 + 64 * LPAD;
  const short* gT0 = WtT + row0 * LPAD + q * 4;
  const short* gT1 = gT0 + 64 * LPAD;
  int d0 = row0 * 40 + q * 8;
  int d1 = d0 + 64 * 40;

  f32x4 acc[2][8];
#pragma unroll
  for (int br = 0; br < 2; ++br)
#pragma unroll
    for (int i = 0; i < 8; ++i) acc[br][i] = (f32x4){0.f, 0.f, 0.f, 0.f};

  // prologue: stage step 0 into buf0; issue x step-0 loads
  {
    int4 a = stage_chunk(gS0), bch = stage_chunk(gS1);
    int4 cch = stage_chunk(gT0), dch = stage_chunk(gT1);
    *(int4*)&wlds[0][0][d0] = a;
    *(int4*)&wlds[0][0][d1] = bch;
    *(int4*)&wlds[0][1][d0] = cch;
    *(int4*)&wlds[0][1][d1] = dch;
  }
  float xc[8];
#pragma unroll
  for (int j = 0; j < 4; ++j) {
    xc[j] = xb[(size_t)(lg * 4 + j) * CC];
    xc[j + 4] = xb[(size_t)(lg * 4 + j + 16) * CC];
  }
  __syncthreads();

  int cur = 0;
  for (int step = 0; step < 23; ++step) {
    bf16x8 bx;
#pragma unroll
    for (int j = 0; j < 8; ++j) bx[j] = f2bf(xc[j]);

    int4 nS0 = {0, 0, 0, 0}, nS1 = nS0, nT0 = nS0, nT1 = nS0;
    float xn[8] = {0.f};
    if (step < 22) {
      int ko = (step + 1) * 32;
      nS0 = stage_chunk(gS0 + ko);
      nS1 = stage_chunk(gS1 + ko);
      nT0 = stage_chunk(gT0 + ko);
      nT1 = stage_chunk(gT1 + ko);
#pragma unroll
      for (int j = 0; j < 4; ++j) {
        int k1 = ko + lg * 4 + j;  // <= 719 always
        int k2 = k1 + 16;          // may hit pad at last step
        xn[j] = xb[(size_t)k1 * CC];
        xn[j + 4] = (k2 < LL) ? xb[(size_t)k2 * CC] : 0.f;
      }
    }

    const short* tS = &wlds[cur][0][0];
    const short* tT = &wlds[cur][1][0];
#pragma unroll
    for (int ht = 0; ht < 8; ++ht) {
      bf16x8 aS = ldsfragP(tS, ht * 16 + lr, lg);
      bf16x8 aT = ldsfragP(tT, ht * 16 + lr, lg);
      acc[0][ht] =
          __builtin_amdgcn_mfma_f32_16x16x32_bf16(aS, bx, acc[0][ht], 0, 0, 0);
      acc[1][ht] =
          __builtin_amdgcn_mfma_f32_16x16x32_bf16(aT, bx, acc[1][ht], 0, 0, 0);
    }

    if (step < 22) {
      short* bS = &wlds[cur ^ 1][0][0];
      short* bT = &wlds[cur ^ 1][1][0];
      *(int4*)&bS[d0] = nS0;
      *(int4*)&bS[d1] = nS1;
      *(int4*)&bT[d0] = nT0;
      *(int4*)&bT[d1] = nT1;
    }
    __syncthreads();
#pragma unroll
    for (int j = 0; j < 8; ++j) xc[j] = xn[j];
    cur ^= 1;
  }

  // epilogue: sigmoid -> bf16 R at shorts [128..255] of each r2 row
  short* rowS = r2s + (size_t)n * 256 + 128;
  short* rowT = r2t + (size_t)n * 256 + 128;
#pragma unroll
  for (int ht = 0; ht < 8; ++ht) {
    int h = ht * 16 + lg * 4;  // D row = (lane>>4)*4 + reg, tile ht
    float4 bS = *(const float4*)&bs1[h];
    float4 bT = *(const float4*)&bt1[h];
    const float* pbS = &bS.x;
    const float* pbT = &bT.x;
    short4 ss, st;
    short* ps = &ss.x;
    short* pt = &st.x;
#pragma unroll
    for (int j = 0; j < 4; ++j) {
      ps[j] = f2bf(1.f / (1.f + __expf(-(acc[0][ht][j] + pbS[j]))));
      pt[j] = f2bf(1.f / (1.f + __expf(-(acc[1][ht][j] + pbT[j]))));
    }
    *(short4*)&rowS[h] = ss;
    *(short4*)&rowT[h] = st;
  }
}

// ---------------------------------------------------------------------------
// Kernel 3: MFMA memory-enhance, both branches in one dispatch (grid.y = 2).
//   32 rows/block, 4 waves. Reads bf16 R from r2[n][128..255]; writes bf16 O
//   to r2[n][0..127].
// ---------------------------------------------------------------------------
__global__ __launch_bounds__(256) void memenh_mfma(
    const short* __restrict__ mSb, const short* __restrict__ mSTb,
    const short* __restrict__ mTb, const short* __restrict__ mTTb,
    short* __restrict__ r2s, short* __restrict__ r2t) {
  int br = blockIdx.y;
  const short* memb = br ? mTb : mSb;
  const short* memTb = br ? mTTb : mSTb;
  short* r2 = br ? r2t : r2s;

  int n0 = blockIdx.x * 32;
  int tid = threadIdx.x;
  int w = tid >> 6;
  int l = tid & 63;
  int lr = l & 15;
  int lg = l >> 4;

  __shared__ float pmax_lds[4][32];
  __shared__ float psum_lds[4][32];
  __shared__ float opart[2][32 * 132];

  // --- B-frags: R rows ---
  bf16x8 brag[2][4];
#pragma unroll
  for (int rt = 0; rt < 2; ++rt) {
    const short* rb = r2 + (size_t)(n0 + lr + 16 * rt) * 256 + 128;
#pragma unroll
    for (int k = 0; k < 4; ++k) brag[rt][k] = ldfrag(rb + k * 32 + lg * 4);
  }

  // --- Phase 1: S^T = mem . R^T ---
  f32x4 accS[2][8];
#pragma unroll
  for (int ft = 0; ft < 8; ++ft) {
    f32x4 a0 = {0.f, 0.f, 0.f, 0.f}, a1 = {0.f, 0.f, 0.f, 0.f};
    const short* mrow = memb + (size_t)(w * 128 + ft * 16 + lr) * 128;
#pragma unroll
    for (int k = 0; k < 4; ++k) {
      bf16x8 af = ldfrag(mrow + k * 32 + lg * 4);
      a0 = __builtin_amdgcn_mfma_f32_16x16x32_bf16(af, brag[0][k], a0, 0, 0, 0);
      a1 = __builtin_amdgcn_mfma_f32_16x16x32_bf16(af, brag[1][k], a1, 0, 0, 0);
    }
    accS[0][ft] = a0;
    accS[1][ft] = a1;
  }

  // --- Phase 2: softmax along f ---
#pragma unroll
  for (int rt = 0; rt < 2; ++rt) {
    float mx = -3.4e38f;
#pragma unroll
    for (int ft = 0; ft < 8; ++ft) {
      f32x4 v = accS[rt][ft];
      mx = fmaxf(mx, fmaxf(fmaxf(v[0], v[1]), fmaxf(v[2], v[3])));
    }
    mx = fmaxf(mx, __shfl_xor(mx, 16));
    mx = fmaxf(mx, __shfl_xor(mx, 32));
    if (lg == 0) pmax_lds[w][rt * 16 + lr] = mx;
  }
  __syncthreads();
#pragma unroll
  for (int rt = 0; rt < 2; ++rt) {
    float gm = fmaxf(fmaxf(pmax_lds[0][rt * 16 + lr], pmax_lds[1][rt * 16 + lr]),
                     fmaxf(pmax_lds[2][rt * 16 + lr], pmax_lds[3][rt * 16 + lr]));
    float s = 0.f;
#pragma unroll
    for (int ft = 0; ft < 8; ++ft) {
      f32x4 v = accS[rt][ft];
#pragma unroll
      for (int j = 0; j < 4; ++j) {
        float e = __expf(v[j] - gm);
        v[j] = e;
        s += e;
      }
      accS[rt][ft] = v;
    }
    s += __shfl_xor(s, 16);
    s += __shfl_xor(s, 32);
    if (lg == 0) psum_lds[w][rt * 16 + lr] = s;
  }

  // --- P^T -> bf16 PV B-frags ---
  bf16x8 pb[2][4];
#pragma unroll
  for (int rt = 0; rt < 2; ++rt)
#pragma unroll
    for (int t = 0; t < 4; ++t) {
      f32x4 e0 = accS[rt][2 * t], e1 = accS[rt][2 * t + 1];
      bf16x8 f;
      f[0] = f2bf(e0[0]); f[1] = f2bf(e0[1]); f[2] = f2bf(e0[2]); f[3] = f2bf(e0[3]);
      f[4] = f2bf(e1[0]); f[5] = f2bf(e1[1]); f[6] = f2bf(e1[2]); f[7] = f2bf(e1[3]);
      pb[rt][t] = f;
    }

  // --- Phase 3: O^T partial = mem^T . P^T ---
  f32x4 accO[8][2];
#pragma unroll
  for (int dt = 0; dt < 8; ++dt) {
    f32x4 o0 = {0.f, 0.f, 0.f, 0.f}, o1 = {0.f, 0.f, 0.f, 0.f};
    const short* mT = memTb + (size_t)(dt * 16 + lr) * MM + w * 128;
#pragma unroll
    for (int t = 0; t < 4; ++t) {
      bf16x8 af = ldfrag(mT + t * 32 + lg * 4);
      o0 = __builtin_amdgcn_mfma_f32_16x16x32_bf16(af, pb[0][t], o0, 0, 0, 0);
      o1 = __builtin_amdgcn_mfma_f32_16x16x32_bf16(af, pb[1][t], o1, 0, 0, 0);
    }
    accO[dt][0] = o0;
    accO[dt][1] = o1;
  }

  // --- Phase 4: cross-wave reduction ---
  if (w >= 2) {
#pragma unroll
    for (int dt = 0; dt < 8; ++dt)
#pragma unroll
      for (int rt = 0; rt < 2; ++rt) {
        f32x4 o = accO[dt][rt];
        *(float4*)&opart[w - 2][(lr + 16 * rt) * 132 + dt * 16 + lg * 4] =
            make_float4(o[0], o[1], o[2], o[3]);
      }
  }
  __syncthreads();
  if (w < 2) {
#pragma unroll
    for (int dt = 0; dt < 8; ++dt)
#pragma unroll
      for (int rt = 0; rt < 2; ++rt) {
        float* p = &opart[w][(lr + 16 * rt) * 132 + dt * 16 + lg * 4];
        float4 qv = *(const float4*)p;
        f32x4 o = accO[dt][rt];
        *(float4*)p = make_float4(o[0] + qv.x, o[1] + qv.y, o[2] + qv.z,
                                  o[3] + qv.w);
      }
  }
  __syncthreads();

  // --- normalize + store O as bf16 to r2[:,0..127] shorts ---
#pragma unroll
  for (int i = 0; i < 2; ++i) {
    int pos = tid + i * 256;          // 0..511
    int r = pos >> 4, dd = (pos & 15) * 8;
    float inv = 1.f / (((psum_lds[0][r] + psum_lds[1][r]) + psum_lds[2][r]) +
                       psum_lds[3][r]);
    float4 a0 = *(const float4*)&opart[0][r * 132 + dd];
    float4 a1 = *(const float4*)&opart[0][r * 132 + dd + 4];
    float4 b0 = *(const float4*)&opart[1][r * 132 + dd];
    float4 b1 = *(const float4*)&opart[1][r * 132 + dd + 4];
    bf16x8 o;
    o[0] = f2bf((a0.x + b0.x) * inv);
    o[1] = f2bf((a0.y + b0.y) * inv);
    o[2] = f2bf((a0.z + b0.z) * inv);
    o[3] = f2bf((a0.w + b0.w) * inv);
    o[4] = f2bf((a1.x + b1.x) * inv);
    o[5] = f2bf((a1.y + b1.y) * inv);
    o[6] = f2bf((a1.z + b1.z) * inv);
    o[7] = f2bf((a1.w + b1.w) * inv);
    *(bf16x8*)&r2[(size_t)(n0 + r) * 256 + dd] = o;
  }
}

// ---------------------------------------------------------------------------
// Kernel 4: MFMA GEMM2 (bf16, K=512 concat) + bias + transposed store.
//   512 thr / 8 waves; block = 128 n x 112 p; grid (321, 3).
//   W2 reg-staged into padded fragment-contiguous LDS (as gemm1).
// ---------------------------------------------------------------------------
__global__ __launch_bounds__(512) void gemm2_mfma(
    const short* __restrict__ r2s, const short* __restrict__ r2t,
    const short* __restrict__ W2b,  // [336][512] bf16
    const float* __restrict__ b2,   // [336]
    float* __restrict__ out) {
  __shared__ __align__(16) short w2lds[2][112 * 40];  // 17.9 KB
  int tid = threadIdx.x;
  int w = tid >> 6, l = tid & 63, lr = l & 15, lg = l >> 4;
  int p0 = blockIdx.y * 112;
  int n = blockIdx.x * 128 + w * 16 + lr;
  int b = n / CC, c = n - b * CC;
  const short* rs = r2s + (size_t)n * 256;
  const short* rt = r2t + (size_t)n * 256;

  bool dostage = tid < 448;  // 112 rows * 4 chunks
  int row = tid >> 2, q = tid & 3;
  const short* gW = W2b + (size_t)(p0 + row) * 512 + q * 4;
  int doff = row * 40 + q * 8;

  f32x4 acc[7];
#pragma unroll
  for (int i = 0; i < 7; ++i) acc[i] = (f32x4){0.f, 0.f, 0.f, 0.f};

  if (dostage) *(int4*)&w2lds[0][doff] = stage_chunk(gW);
  __syncthreads();

  int cur = 0;
  for (int step = 0; step < 16; ++step) {
    int k0 = step * 32;
    const short* rrow = ((k0 < 256) ? rs : rt) + (k0 & 255);
    bf16x8 bfr = ldfrag(rrow + lg * 4);
    int4 nxt = {0, 0, 0, 0};
    if (step < 15 && dostage) nxt = stage_chunk(gW + (step + 1) * 32);
    const short* tw = &w2lds[cur][0];
#pragma unroll
    for (int pt = 0; pt < 7; ++pt) {
      bf16x8 a = ldsfragP(tw, pt * 16 + lr, lg);
      acc[pt] = __builtin_amdgcn_mfma_f32_16x16x32_bf16(a, bfr, acc[pt], 0, 0, 0);
    }
    if (step < 15 && dostage) *(int4*)&w2lds[cur ^ 1][doff] = nxt;
    __syncthreads();
    cur ^= 1;
  }

  size_t obase = (size_t)b * ((size_t)PP * CC) + c;
#pragma unroll
  for (int pt = 0; pt < 7; ++pt) {
    int p = p0 + pt * 16 + lg * 4;
    float4 bias = *(const float4*)&b2[p];
    const float* pb = &bias.x;
#pragma unroll
    for (int j = 0; j < 4; ++j) {
      out[obase + (size_t)(p + j) * CC] = acc[pt][j] + pb[j];
    }
  }
}

// ---------------------------------------------------------------------------
extern "C" void kernel_launch(void* const* d_in, const int* in_sizes, int n_in,
                              void* d_out, int out_size, void* d_ws, size_t ws_size,
                              hipStream_t stream) {
  const float* x    = (const float*)d_in[0];
  const float* Ws1  = (const float*)d_in[1];
  const float* bs1  = (const float*)d_in[2];
  const float* Ws2  = (const float*)d_in[3];
  const float* bs2  = (const float*)d_in[4];
  const float* Wt1  = (const float*)d_in[5];
  const float* bt1  = (const float*)d_in[6];
  const float* Wt2  = (const float*)d_in[7];
  const float* bt2  = (const float*)d_in[8];
  const float* memS = (const float*)d_in[9];
  const float* memT = (const float*)d_in[10];
  float* out = (float*)d_out;

  const size_t N = (size_t)BB * CC;          // 41088
  short* r2s  = (short*)d_ws;                // [N][256] bf16: [O | R]
  short* r2t  = r2s + N * 256;
  short* WsTb = r2t + N * 256;               // [H][LPAD] bf16
  short* WtTb = WsTb + (size_t)HH * LPAD;
  short* mSb  = WtTb + (size_t)HH * LPAD;    // [512][128] bf16
  short* mSTb = mSb + (size_t)MM * HH;       // [128][512]
  short* mTb  = mSTb + (size_t)MM * HH;
  short* mTTb = mTb + (size_t)MM * HH;
  short* W2b  = mTTb + (size_t)MM * HH;      // [336][512] bf16
  float* b2   = (float*)(W2b + (size_t)PP * 512);
  // total ~= 43 MB

  // 1. precompute weights / conversions
  weff_kernel<<<(HH * LPAD) / 256, 256, 0, stream>>>(Ws1, Wt1, WsTb, WtTb);
  memcvt_kernel<<<(MM * HH) / 256, 256, 0, stream>>>(memS, memT, mSb, mSTb,
                                                     mTb, mTTb);
  w2cvt_kernel<<<(PP * 512) / 256, 256, 0, stream>>>(Ws2, Wt2, bs2, bt2, W2b, b2);

  // 2. MFMA GEMM1 + sigmoid (both branches), grid 642
  gemm1_mfma<<<642, 256, 0, stream>>>(x, WsTb, WtTb, bs1, bt1, r2s, r2t);

  // 3. MFMA memory enhance, both branches in one dispatch
  dim3 g3((unsigned)(N / 32), 2);  // (1284, 2)
  memenh_mfma<<<g3, 256, 0, stream>>>(mSb, mSTb, mTb, mTTb, r2s, r2t);

  // 4. MFMA GEMM2 + bias + transposed store
  dim3 g2(321, 3);
  gemm2_mfma<<<g2, 512, 0, stream>>>(r2s, r2t, W2b, b2, out);
}

// Round 6
// 234.443 us; speedup vs baseline: 7.0050x; 1.2771x over previous
//
#include <hip/hip_runtime.h>
#include <math.h>

#define BB 128
#define LL 720
#define CC 321
#define HH 128
#define PP 336
#define MM 512
#define LPAD 736  // 720 padded to multiple of 32

typedef __attribute__((ext_vector_type(8))) short bf16x8;
typedef __attribute__((ext_vector_type(4))) float f32x4;

__device__ __forceinline__ short f2bf(float x) {
  unsigned u = __builtin_bit_cast(unsigned, x);
  u = (u + 0x7FFFu + ((u >> 16) & 1u)) >> 16;
  return (short)u;
}

// load an 8-element bf16 MFMA fragment from global: elems 0..3 at p, 4..7 at p+16
__device__ __forceinline__ bf16x8 ldfrag(const short* p) {
  short4 a = *(const short4*)p;
  short4 b = *(const short4*)(p + 16);
  bf16x8 r;
  r[0] = a.x; r[1] = a.y; r[2] = a.z; r[3] = a.w;
  r[4] = b.x; r[5] = b.y; r[6] = b.z; r[7] = b.w;
  return r;
}

// Stage one 16B "fragment chunk" from global W row: 8B at g, 8B at g+16.
__device__ __forceinline__ int4 stage_chunk(const short* g) {
  int2 lo = *(const int2*)g;
  int2 hi = *(const int2*)(g + 16);
  int4 r;
  r.x = lo.x; r.y = lo.y; r.z = hi.x; r.w = hi.y;
  return r;
}

// Fragment read from padded LDS tile: rows of 40 shorts (80 B), fragment for
// (row h, lane-group lg) is 8 contiguous shorts at h*40 + lg*8 -> ds_read_b128.
__device__ __forceinline__ bf16x8 ldsfragP(const short* tile, int h, int lg) {
  return *(const bf16x8*)&tile[h * 40 + lg * 8];
}

// ---------------------------------------------------------------------------
// Kernel 1: effective (smeared) weights -> bf16 [H][LPAD] (zero-padded tail).
// ---------------------------------------------------------------------------
__global__ void weff_kernel(const float* __restrict__ Ws1,
                            const float* __restrict__ Wt1,
                            short* __restrict__ WsT,
                            short* __restrict__ WtT) {
  int idx = blockIdx.x * 256 + threadIdx.x;
  if (idx >= HH * LPAD) return;
  int j = idx % LPAD, h = idx / LPAD;
  if (j >= LL) { WsT[idx] = 0; WtT[idx] = 0; return; }
  float ss = 0.f, st = 0.f;
  if (j == 0) {
    for (int l = 0; l <= 12; ++l) {
      float w = 13.f - (float)l;
      ss += w * Ws1[h * LL + l];
      st += w * Wt1[h * LL + l];
    }
  } else if (j == LL - 1) {
    for (int d = 0; d <= 12; ++d) {
      float w = 13.f - (float)d;
      ss += w * Ws1[h * LL + LL - 1 - d];
      st += w * Wt1[h * LL + LL - 1 - d];
    }
  } else {
    int lo = j - 12 < 0 ? 0 : j - 12;
    int hi = j + 12 > LL - 1 ? LL - 1 : j + 12;
    for (int l = lo; l <= hi; ++l) {
      ss += Ws1[h * LL + l];
      st += Wt1[h * LL + l];
    }
  }
  ss *= (1.f / 25.f);
  st *= (1.f / 25.f);
  WsT[idx] = f2bf(Ws1[h * LL + j] - ss);
  WtT[idx] = f2bf(st);
}

// ---------------------------------------------------------------------------
// Kernel 1b: mem -> bf16 natural + transposed.
// ---------------------------------------------------------------------------
__global__ void memcvt_kernel(const float* __restrict__ memS,
                              const float* __restrict__ memT,
                              short* __restrict__ mSb, short* __restrict__ mSTb,
                              short* __restrict__ mTb, short* __restrict__ mTTb) {
  int i = blockIdx.x * 256 + threadIdx.x;
  if (i >= MM * HH) return;
  int f = i >> 7, d = i & 127;
  short vs = f2bf(memS[i]);
  short vt = f2bf(memT[i]);
  mSb[i] = vs;
  mSTb[d * MM + f] = vs;
  mTb[i] = vt;
  mTTb[d * MM + f] = vt;
}

// ---------------------------------------------------------------------------
// Kernel 1c: W2cat bf16 [336][512] (k<256 = seasonal, else trend) + bias sum.
// ---------------------------------------------------------------------------
__global__ void w2cvt_kernel(const float* __restrict__ Ws2,
                             const float* __restrict__ Wt2,
                             const float* __restrict__ bs2,
                             const float* __restrict__ bt2,
                             short* __restrict__ W2b, float* __restrict__ b2) {
  int i = blockIdx.x * 256 + threadIdx.x;
  if (i < PP) b2[i] = bs2[i] + bt2[i];
  if (i >= PP * 512) return;
  int p = i >> 9, k = i & 511;
  float v = (k < 256) ? Ws2[p * 256 + k] : Wt2[p * 256 + (k - 256)];
  W2b[i] = f2bf(v);
}

// ---------------------------------------------------------------------------
// Kernel 2: MFMA dual-branch GEMM1 + sigmoid.  (unchanged from round 5)
// ---------------------------------------------------------------------------
__global__ __launch_bounds__(256) void gemm1_mfma(
    const float* __restrict__ x,
    const short* __restrict__ WsT, const short* __restrict__ WtT,
    const float* __restrict__ bs1, const float* __restrict__ bt1,
    short* __restrict__ r2s, short* __restrict__ r2t) {
  __shared__ __align__(16) short wlds[2][2][128 * 40];  // 40 KB
  int tid = threadIdx.x;
  int w = tid >> 6, l = tid & 63, lr = l & 15, lg = l >> 4;
  int n = blockIdx.x * 64 + w * 16 + lr;  // 41088 = 642*64 exact
  int b = n / CC;
  int c = n - b * CC;
  const float* xb = x + (size_t)b * (LL * CC) + c;

  int row0 = tid >> 2, q = tid & 3;
  const short* gS0 = WsT + row0 * LPAD + q * 4;
  const short* gS1 = gS0 + 64 * LPAD;
  const short* gT0 = WtT + row0 * LPAD + q * 4;
  const short* gT1 = gT0 + 64 * LPAD;
  int d0 = row0 * 40 + q * 8;
  int d1 = d0 + 64 * 40;

  f32x4 acc[2][8];
#pragma unroll
  for (int br = 0; br < 2; ++br)
#pragma unroll
    for (int i = 0; i < 8; ++i) acc[br][i] = (f32x4){0.f, 0.f, 0.f, 0.f};

  {
    int4 a = stage_chunk(gS0), bch = stage_chunk(gS1);
    int4 cch = stage_chunk(gT0), dch = stage_chunk(gT1);
    *(int4*)&wlds[0][0][d0] = a;
    *(int4*)&wlds[0][0][d1] = bch;
    *(int4*)&wlds[0][1][d0] = cch;
    *(int4*)&wlds[0][1][d1] = dch;
  }
  float xc[8];
#pragma unroll
  for (int j = 0; j < 4; ++j) {
    xc[j] = xb[(size_t)(lg * 4 + j) * CC];
    xc[j + 4] = xb[(size_t)(lg * 4 + j + 16) * CC];
  }
  __syncthreads();

  int cur = 0;
  for (int step = 0; step < 23; ++step) {
    bf16x8 bx;
#pragma unroll
    for (int j = 0; j < 8; ++j) bx[j] = f2bf(xc[j]);

    int4 nS0 = {0, 0, 0, 0}, nS1 = nS0, nT0 = nS0, nT1 = nS0;
    float xn[8] = {0.f};
    if (step < 22) {
      int ko = (step + 1) * 32;
      nS0 = stage_chunk(gS0 + ko);
      nS1 = stage_chunk(gS1 + ko);
      nT0 = stage_chunk(gT0 + ko);
      nT1 = stage_chunk(gT1 + ko);
#pragma unroll
      for (int j = 0; j < 4; ++j) {
        int k1 = ko + lg * 4 + j;
        int k2 = k1 + 16;
        xn[j] = xb[(size_t)k1 * CC];
        xn[j + 4] = (k2 < LL) ? xb[(size_t)k2 * CC] : 0.f;
      }
    }

    const short* tS = &wlds[cur][0][0];
    const short* tT = &wlds[cur][1][0];
#pragma unroll
    for (int ht = 0; ht < 8; ++ht) {
      bf16x8 aS = ldsfragP(tS, ht * 16 + lr, lg);
      bf16x8 aT = ldsfragP(tT, ht * 16 + lr, lg);
      acc[0][ht] =
          __builtin_amdgcn_mfma_f32_16x16x32_bf16(aS, bx, acc[0][ht], 0, 0, 0);
      acc[1][ht] =
          __builtin_amdgcn_mfma_f32_16x16x32_bf16(aT, bx, acc[1][ht], 0, 0, 0);
    }

    if (step < 22) {
      short* bS = &wlds[cur ^ 1][0][0];
      short* bT = &wlds[cur ^ 1][1][0];
      *(int4*)&bS[d0] = nS0;
      *(int4*)&bS[d1] = nS1;
      *(int4*)&bT[d0] = nT0;
      *(int4*)&bT[d1] = nT1;
    }
    __syncthreads();
#pragma unroll
    for (int j = 0; j < 8; ++j) xc[j] = xn[j];
    cur ^= 1;
  }

  short* rowS = r2s + (size_t)n * 256 + 128;
  short* rowT = r2t + (size_t)n * 256 + 128;
#pragma unroll
  for (int ht = 0; ht < 8; ++ht) {
    int h = ht * 16 + lg * 4;
    float4 bS = *(const float4*)&bs1[h];
    float4 bT = *(const float4*)&bt1[h];
    const float* pbS = &bS.x;
    const float* pbT = &bT.x;
    short4 ss, st;
    short* ps = &ss.x;
    short* pt = &st.x;
#pragma unroll
    for (int j = 0; j < 4; ++j) {
      ps[j] = f2bf(1.f / (1.f + __expf(-(acc[0][ht][j] + pbS[j]))));
      pt[j] = f2bf(1.f / (1.f + __expf(-(acc[1][ht][j] + pbT[j]))));
    }
    *(short4*)&rowS[h] = ss;
    *(short4*)&rowT[h] = st;
  }
}

// ---------------------------------------------------------------------------
// Kernel 3 (v3): LDS-tiled MFMA memory-enhance.
//   Grid (642, 2); 256 thr / 4 waves; block = 64 rows; wave w owns 16 rows
//   and ALL 512 f -> softmax is wave-local (shfl only, no LDS reduce).
//   f staged in 128-wide tiles (32 KB, fragment-contiguous, 136-short row
//   stride -> bank-balanced b128 on write and read), shared by all 4 waves.
//   Pass 1: scores; pass 2: PV with P-frags direct from exp'd score regs.
// ---------------------------------------------------------------------------
__global__ __launch_bounds__(256) void memenh_mfma(
    const short* __restrict__ mSb, const short* __restrict__ mSTb,
    const short* __restrict__ mTb, const short* __restrict__ mTTb,
    short* __restrict__ r2s, short* __restrict__ r2t) {
  int br = blockIdx.y;
  const short* memb = br ? mTb : mSb;
  const short* memTb = br ? mTTb : mSTb;
  short* r2 = br ? r2t : r2s;

  __shared__ __align__(16) short tile[128 * 136];  // 34816 B
  int tid = threadIdx.x;
  int w = tid >> 6, l = tid & 63, lr = l & 15, lg = l >> 4;
  int n = blockIdx.x * 64 + w * 16 + lr;

  // --- B-frags: this wave's 16 R rows ---
  bf16x8 brag[4];
  {
    const short* rb = r2 + (size_t)n * 256 + 128;
#pragma unroll
    for (int k = 0; k < 4; ++k) brag[k] = ldfrag(rb + k * 32 + lg * 4);
  }

  // --- Pass 1: scores S^T = mem . R^T, f-tiles of 128 ---
  f32x4 accS[32];
#pragma unroll
  for (int ftile = 0; ftile < 4; ++ftile) {
    if (ftile) __syncthreads();
#pragma unroll
    for (int i = 0; i < 8; ++i) {
      int e = i * 256 + tid;
      int row = e >> 4, ci = e & 15;
      int k = ci >> 2, lgc = ci & 3;
      const short* g = memb + (size_t)(ftile * 128 + row) * 128 + k * 32 + lgc * 4;
      *(int4*)&tile[row * 136 + ci * 8] = stage_chunk(g);
    }
    __syncthreads();
#pragma unroll
    for (int ft16 = 0; ft16 < 8; ++ft16) {
      f32x4 a = {0.f, 0.f, 0.f, 0.f};
#pragma unroll
      for (int k = 0; k < 4; ++k) {
        bf16x8 af = *(const bf16x8*)&tile[(ft16 * 16 + lr) * 136 + k * 32 + lg * 8];
        a = __builtin_amdgcn_mfma_f32_16x16x32_bf16(af, brag[k], a, 0, 0, 0);
      }
      accS[ftile * 8 + ft16] = a;
    }
  }

  // --- softmax along f: wave-local (in-lane + shfl across lg groups) ---
  float mx = -3.4e38f;
#pragma unroll
  for (int i = 0; i < 32; ++i) {
    f32x4 v = accS[i];
    mx = fmaxf(mx, fmaxf(fmaxf(v[0], v[1]), fmaxf(v[2], v[3])));
  }
  mx = fmaxf(mx, __shfl_xor(mx, 16));
  mx = fmaxf(mx, __shfl_xor(mx, 32));
  float s = 0.f;
#pragma unroll
  for (int i = 0; i < 32; ++i) {
    f32x4 v = accS[i];
#pragma unroll
    for (int j = 0; j < 4; ++j) {
      float e = __expf(v[j] - mx);
      v[j] = e;
      s += e;
    }
    accS[i] = v;
  }
  s += __shfl_xor(s, 16);
  s += __shfl_xor(s, 32);
  float inv = 1.f / s;

  // --- Pass 2: O^T = mem^T . P^T, f-tiles of 128 ---
  f32x4 accO[8];
#pragma unroll
  for (int i = 0; i < 8; ++i) accO[i] = (f32x4){0.f, 0.f, 0.f, 0.f};
#pragma unroll
  for (int ftile = 0; ftile < 4; ++ftile) {
    __syncthreads();
#pragma unroll
    for (int i = 0; i < 8; ++i) {
      int e = i * 256 + tid;
      int row = e >> 4, ci = e & 15;
      int k = ci >> 2, lgc = ci & 3;
      const short* g = memTb + (size_t)row * MM + ftile * 128 + k * 32 + lgc * 4;
      *(int4*)&tile[row * 136 + ci * 8] = stage_chunk(g);
    }
    __syncthreads();
    bf16x8 pb[4];
#pragma unroll
    for (int t = 0; t < 4; ++t) {
      f32x4 e0 = accS[ftile * 8 + 2 * t], e1 = accS[ftile * 8 + 2 * t + 1];
      bf16x8 f;
      f[0] = f2bf(e0[0]); f[1] = f2bf(e0[1]); f[2] = f2bf(e0[2]); f[3] = f2bf(e0[3]);
      f[4] = f2bf(e1[0]); f[5] = f2bf(e1[1]); f[6] = f2bf(e1[2]); f[7] = f2bf(e1[3]);
      pb[t] = f;
    }
#pragma unroll
    for (int dt = 0; dt < 8; ++dt) {
#pragma unroll
      for (int t = 0; t < 4; ++t) {
        bf16x8 af = *(const bf16x8*)&tile[(dt * 16 + lr) * 136 + t * 32 + lg * 8];
        accO[dt] = __builtin_amdgcn_mfma_f32_16x16x32_bf16(af, pb[t], accO[dt], 0, 0, 0);
      }
    }
  }

  // --- normalize + store O as bf16 to r2[n][0..127] ---
  short* rowO = r2 + (size_t)n * 256;
#pragma unroll
  for (int dt = 0; dt < 8; ++dt) {
    short4 o;
    o.x = f2bf(accO[dt][0] * inv);
    o.y = f2bf(accO[dt][1] * inv);
    o.z = f2bf(accO[dt][2] * inv);
    o.w = f2bf(accO[dt][3] * inv);
    *(short4*)&rowO[dt * 16 + lg * 4] = o;
  }
}

// ---------------------------------------------------------------------------
// Kernel 4: MFMA GEMM2 (bf16, K=512 concat) + bias + transposed store.
//   (unchanged from round 5)
// ---------------------------------------------------------------------------
__global__ __launch_bounds__(512) void gemm2_mfma(
    const short* __restrict__ r2s, const short* __restrict__ r2t,
    const short* __restrict__ W2b,  // [336][512] bf16
    const float* __restrict__ b2,   // [336]
    float* __restrict__ out) {
  __shared__ __align__(16) short w2lds[2][112 * 40];  // 17.9 KB
  int tid = threadIdx.x;
  int w = tid >> 6, l = tid & 63, lr = l & 15, lg = l >> 4;
  int p0 = blockIdx.y * 112;
  int n = blockIdx.x * 128 + w * 16 + lr;
  int b = n / CC, c = n - b * CC;
  const short* rs = r2s + (size_t)n * 256;
  const short* rt = r2t + (size_t)n * 256;

  bool dostage = tid < 448;
  int row = tid >> 2, q = tid & 3;
  const short* gW = W2b + (size_t)(p0 + row) * 512 + q * 4;
  int doff = row * 40 + q * 8;

  f32x4 acc[7];
#pragma unroll
  for (int i = 0; i < 7; ++i) acc[i] = (f32x4){0.f, 0.f, 0.f, 0.f};

  if (dostage) *(int4*)&w2lds[0][doff] = stage_chunk(gW);
  __syncthreads();

  int cur = 0;
  for (int step = 0; step < 16; ++step) {
    int k0 = step * 32;
    const short* rrow = ((k0 < 256) ? rs : rt) + (k0 & 255);
    bf16x8 bfr = ldfrag(rrow + lg * 4);
    int4 nxt = {0, 0, 0, 0};
    if (step < 15 && dostage) nxt = stage_chunk(gW + (step + 1) * 32);
    const short* tw = &w2lds[cur][0];
#pragma unroll
    for (int pt = 0; pt < 7; ++pt) {
      bf16x8 a = ldsfragP(tw, pt * 16 + lr, lg);
      acc[pt] = __builtin_amdgcn_mfma_f32_16x16x32_bf16(a, bfr, acc[pt], 0, 0, 0);
    }
    if (step < 15 && dostage) *(int4*)&w2lds[cur ^ 1][doff] = nxt;
    __syncthreads();
    cur ^= 1;
  }

  size_t obase = (size_t)b * ((size_t)PP * CC) + c;
#pragma unroll
  for (int pt = 0; pt < 7; ++pt) {
    int p = p0 + pt * 16 + lg * 4;
    float4 bias = *(const float4*)&b2[p];
    const float* pb = &bias.x;
#pragma unroll
    for (int j = 0; j < 4; ++j) {
      out[obase + (size_t)(p + j) * CC] = acc[pt][j] + pb[j];
    }
  }
}

// ---------------------------------------------------------------------------
extern "C" void kernel_launch(void* const* d_in, const int* in_sizes, int n_in,
                              void* d_out, int out_size, void* d_ws, size_t ws_size,
                              hipStream_t stream) {
  const float* x    = (const float*)d_in[0];
  const float* Ws1  = (const float*)d_in[1];
  const float* bs1  = (const float*)d_in[2];
  const float* Ws2  = (const float*)d_in[3];
  const float* bs2  = (const float*)d_in[4];
  const float* Wt1  = (const float*)d_in[5];
  const float* bt1  = (const float*)d_in[6];
  const float* Wt2  = (const float*)d_in[7];
  const float* bt2  = (const float*)d_in[8];
  const float* memS = (const float*)d_in[9];
  const float* memT = (const float*)d_in[10];
  float* out = (float*)d_out;

  const size_t N = (size_t)BB * CC;          // 41088
  short* r2s  = (short*)d_ws;                // [N][256] bf16: [O | R]
  short* r2t  = r2s + N * 256;
  short* WsTb = r2t + N * 256;               // [H][LPAD] bf16
  short* WtTb = WsTb + (size_t)HH * LPAD;
  short* mSb  = WtTb + (size_t)HH * LPAD;    // [512][128] bf16
  short* mSTb = mSb + (size_t)MM * HH;       // [128][512]
  short* mTb  = mSTb + (size_t)MM * HH;
  short* mTTb = mTb + (size_t)MM * HH;
  short* W2b  = mTTb + (size_t)MM * HH;      // [336][512] bf16
  float* b2   = (float*)(W2b + (size_t)PP * 512);

  // 1. precompute weights / conversions
  weff_kernel<<<(HH * LPAD) / 256, 256, 0, stream>>>(Ws1, Wt1, WsTb, WtTb);
  memcvt_kernel<<<(MM * HH) / 256, 256, 0, stream>>>(memS, memT, mSb, mSTb,
                                                     mTb, mTTb);
  w2cvt_kernel<<<(PP * 512) / 256, 256, 0, stream>>>(Ws2, Wt2, bs2, bt2, W2b, b2);

  // 2. MFMA GEMM1 + sigmoid (both branches), grid 642
  gemm1_mfma<<<642, 256, 0, stream>>>(x, WsTb, WtTb, bs1, bt1, r2s, r2t);

  // 3. LDS-tiled MFMA memory enhance, both branches in one dispatch
  dim3 g3(642, 2);
  memenh_mfma<<<g3, 256, 0, stream>>>(mSb, mSTb, mTb, mTTb, r2s, r2t);

  // 4. MFMA GEMM2 + bias + transposed store
  dim3 g2(321, 3);
  gemm2_mfma<<<g2, 512, 0, stream>>>(r2s, r2t, W2b, b2, out);
}

// Round 7
// 151.960 us; speedup vs baseline: 10.8073x; 1.5428x over previous
//
#include <hip/hip_runtime.h>
#include <math.h>

#define BB 128
#define LL 720
#define CC 321
#define HH 128
#define PP 336
#define MM 512
#define LPAD 736  // 720 padded to multiple of 32

typedef __attribute__((ext_vector_type(8))) short bf16x8;
typedef __attribute__((ext_vector_type(4))) float f32x4;

__device__ __forceinline__ short f2bf(float x) {
  unsigned u = __builtin_bit_cast(unsigned, x);
  u = (u + 0x7FFFu + ((u >> 16) & 1u)) >> 16;
  return (short)u;
}

// load an 8-element bf16 MFMA fragment from global: elems 0..3 at p, 4..7 at p+16
__device__ __forceinline__ bf16x8 ldfrag(const short* p) {
  short4 a = *(const short4*)p;
  short4 b = *(const short4*)(p + 16);
  bf16x8 r;
  r[0] = a.x; r[1] = a.y; r[2] = a.z; r[3] = a.w;
  r[4] = b.x; r[5] = b.y; r[6] = b.z; r[7] = b.w;
  return r;
}

// Stage one 16B "fragment chunk" from global W row: 8B at g, 8B at g+16.
__device__ __forceinline__ int4 stage_chunk(const short* g) {
  int2 lo = *(const int2*)g;
  int2 hi = *(const int2*)(g + 16);
  int4 r;
  r.x = lo.x; r.y = lo.y; r.z = hi.x; r.w = hi.y;
  return r;
}

// Fragment read from padded LDS tile: rows of 40 shorts (80 B), fragment for
// (row h, lane-group lg) is 8 contiguous shorts at h*40 + lg*8 -> ds_read_b128.
__device__ __forceinline__ bf16x8 ldsfragP(const short* tile, int h, int lg) {
  return *(const bf16x8*)&tile[h * 40 + lg * 8];
}

// async global->LDS, 16 bytes per lane; lds ptr must be wave-uniform
__device__ __forceinline__ void gload_lds16(const short* g, short* l) {
  __builtin_amdgcn_global_load_lds(
      (const __attribute__((address_space(1))) unsigned int*)g,
      (__attribute__((address_space(3))) unsigned int*)l, 16, 0, 0);
}

// ---------------------------------------------------------------------------
// Kernel 1: effective (smeared) weights -> bf16 [H][LPAD] (zero-padded tail).
// ---------------------------------------------------------------------------
__global__ void weff_kernel(const float* __restrict__ Ws1,
                            const float* __restrict__ Wt1,
                            short* __restrict__ WsT,
                            short* __restrict__ WtT) {
  int idx = blockIdx.x * 256 + threadIdx.x;
  if (idx >= HH * LPAD) return;
  int j = idx % LPAD, h = idx / LPAD;
  if (j >= LL) { WsT[idx] = 0; WtT[idx] = 0; return; }
  float ss = 0.f, st = 0.f;
  if (j == 0) {
    for (int l = 0; l <= 12; ++l) {
      float w = 13.f - (float)l;
      ss += w * Ws1[h * LL + l];
      st += w * Wt1[h * LL + l];
    }
  } else if (j == LL - 1) {
    for (int d = 0; d <= 12; ++d) {
      float w = 13.f - (float)d;
      ss += w * Ws1[h * LL + LL - 1 - d];
      st += w * Wt1[h * LL + LL - 1 - d];
    }
  } else {
    int lo = j - 12 < 0 ? 0 : j - 12;
    int hi = j + 12 > LL - 1 ? LL - 1 : j + 12;
    for (int l = lo; l <= hi; ++l) {
      ss += Ws1[h * LL + l];
      st += Wt1[h * LL + l];
    }
  }
  ss *= (1.f / 25.f);
  st *= (1.f / 25.f);
  WsT[idx] = f2bf(Ws1[h * LL + j] - ss);
  WtT[idx] = f2bf(st);
}

// ---------------------------------------------------------------------------
// Kernel 1b (v2): build staged mem images for memenh.
//   Per branch: 8 tiles (even = mem f-tile, odd = mem^T f-tile) of 2048
//   16B chunks. Chunk c of a tile: row = c>>4, slot = c&15,
//   slot' = slot ^ (row&7)  (XOR bank-swizzle baked into the image),
//   k = slot'>>2, lg = slot'&3; payload = the 8-bf16 MFMA fragment
//   (halves at k*32+lg*4 and +16). memenh copies tiles linearly via
//   global_load_lds and reads with the same XOR.
// ---------------------------------------------------------------------------
__global__ void memstage_kernel(const float* __restrict__ memS,
                                const float* __restrict__ memT,
                                short* __restrict__ stgS,
                                short* __restrict__ stgT) {
  int e = blockIdx.x * 256 + threadIdx.x;  // 0..32767
  int br = e >> 14;
  int s = e & 16383;
  const float* src = br ? memT : memS;
  short* dst = br ? stgT : stgS;
  int tt = s >> 11;                        // tile 0..7
  int c = s & 2047;
  int row = c >> 4, slot = c & 15;
  int sp = slot ^ (row & 7);
  int k = sp >> 2, lg = sp & 3;
  int ft = tt >> 1;
  short out[8];
  if ((tt & 1) == 0) {
    const float* r0 = src + (size_t)(ft * 128 + row) * 128 + k * 32 + lg * 4;
#pragma unroll
    for (int j = 0; j < 4; ++j) {
      out[j] = f2bf(r0[j]);
      out[j + 4] = f2bf(r0[16 + j]);
    }
  } else {
    int fbase = ft * 128 + k * 32 + lg * 4;
#pragma unroll
    for (int j = 0; j < 4; ++j) {
      out[j] = f2bf(src[(size_t)(fbase + j) * 128 + row]);
      out[j + 4] = f2bf(src[(size_t)(fbase + 16 + j) * 128 + row]);
    }
  }
  short4 a = make_short4(out[0], out[1], out[2], out[3]);
  short4 b = make_short4(out[4], out[5], out[6], out[7]);
  *(short4*)&dst[(size_t)s * 8] = a;
  *(short4*)&dst[(size_t)s * 8 + 4] = b;
}

// ---------------------------------------------------------------------------
// Kernel 1c: W2cat bf16 [336][512] (k<256 = seasonal, else trend) + bias sum.
// ---------------------------------------------------------------------------
__global__ void w2cvt_kernel(const float* __restrict__ Ws2,
                             const float* __restrict__ Wt2,
                             const float* __restrict__ bs2,
                             const float* __restrict__ bt2,
                             short* __restrict__ W2b, float* __restrict__ b2) {
  int i = blockIdx.x * 256 + threadIdx.x;
  if (i < PP) b2[i] = bs2[i] + bt2[i];
  if (i >= PP * 512) return;
  int p = i >> 9, k = i & 511;
  float v = (k < 256) ? Ws2[p * 256 + k] : Wt2[p * 256 + (k - 256)];
  W2b[i] = f2bf(v);
}

// ---------------------------------------------------------------------------
// Kernel 2: MFMA dual-branch GEMM1 + sigmoid.  (unchanged)
// ---------------------------------------------------------------------------
__global__ __launch_bounds__(256) void gemm1_mfma(
    const float* __restrict__ x,
    const short* __restrict__ WsT, const short* __restrict__ WtT,
    const float* __restrict__ bs1, const float* __restrict__ bt1,
    short* __restrict__ r2s, short* __restrict__ r2t) {
  __shared__ __align__(16) short wlds[2][2][128 * 40];  // 40 KB
  int tid = threadIdx.x;
  int w = tid >> 6, l = tid & 63, lr = l & 15, lg = l >> 4;
  int n = blockIdx.x * 64 + w * 16 + lr;
  int b = n / CC;
  int c = n - b * CC;
  const float* xb = x + (size_t)b * (LL * CC) + c;

  int row0 = tid >> 2, q = tid & 3;
  const short* gS0 = WsT + row0 * LPAD + q * 4;
  const short* gS1 = gS0 + 64 * LPAD;
  const short* gT0 = WtT + row0 * LPAD + q * 4;
  const short* gT1 = gT0 + 64 * LPAD;
  int d0 = row0 * 40 + q * 8;
  int d1 = d0 + 64 * 40;

  f32x4 acc[2][8];
#pragma unroll
  for (int br = 0; br < 2; ++br)
#pragma unroll
    for (int i = 0; i < 8; ++i) acc[br][i] = (f32x4){0.f, 0.f, 0.f, 0.f};

  {
    int4 a = stage_chunk(gS0), bch = stage_chunk(gS1);
    int4 cch = stage_chunk(gT0), dch = stage_chunk(gT1);
    *(int4*)&wlds[0][0][d0] = a;
    *(int4*)&wlds[0][0][d1] = bch;
    *(int4*)&wlds[0][1][d0] = cch;
    *(int4*)&wlds[0][1][d1] = dch;
  }
  float xc[8];
#pragma unroll
  for (int j = 0; j < 4; ++j) {
    xc[j] = xb[(size_t)(lg * 4 + j) * CC];
    xc[j + 4] = xb[(size_t)(lg * 4 + j + 16) * CC];
  }
  __syncthreads();

  int cur = 0;
  for (int step = 0; step < 23; ++step) {
    bf16x8 bx;
#pragma unroll
    for (int j = 0; j < 8; ++j) bx[j] = f2bf(xc[j]);

    int4 nS0 = {0, 0, 0, 0}, nS1 = nS0, nT0 = nS0, nT1 = nS0;
    float xn[8] = {0.f};
    if (step < 22) {
      int ko = (step + 1) * 32;
      nS0 = stage_chunk(gS0 + ko);
      nS1 = stage_chunk(gS1 + ko);
      nT0 = stage_chunk(gT0 + ko);
      nT1 = stage_chunk(gT1 + ko);
#pragma unroll
      for (int j = 0; j < 4; ++j) {
        int k1 = ko + lg * 4 + j;
        int k2 = k1 + 16;
        xn[j] = xb[(size_t)k1 * CC];
        xn[j + 4] = (k2 < LL) ? xb[(size_t)k2 * CC] : 0.f;
      }
    }

    const short* tS = &wlds[cur][0][0];
    const short* tT = &wlds[cur][1][0];
#pragma unroll
    for (int ht = 0; ht < 8; ++ht) {
      bf16x8 aS = ldsfragP(tS, ht * 16 + lr, lg);
      bf16x8 aT = ldsfragP(tT, ht * 16 + lr, lg);
      acc[0][ht] =
          __builtin_amdgcn_mfma_f32_16x16x32_bf16(aS, bx, acc[0][ht], 0, 0, 0);
      acc[1][ht] =
          __builtin_amdgcn_mfma_f32_16x16x32_bf16(aT, bx, acc[1][ht], 0, 0, 0);
    }

    if (step < 22) {
      short* bS = &wlds[cur ^ 1][0][0];
      short* bT = &wlds[cur ^ 1][1][0];
      *(int4*)&bS[d0] = nS0;
      *(int4*)&bS[d1] = nS1;
      *(int4*)&bT[d0] = nT0;
      *(int4*)&bT[d1] = nT1;
    }
    __syncthreads();
#pragma unroll
    for (int j = 0; j < 8; ++j) xc[j] = xn[j];
    cur ^= 1;
  }

  short* rowS = r2s + (size_t)n * 256 + 128;
  short* rowT = r2t + (size_t)n * 256 + 128;
#pragma unroll
  for (int ht = 0; ht < 8; ++ht) {
    int h = ht * 16 + lg * 4;
    float4 bS = *(const float4*)&bs1[h];
    float4 bT = *(const float4*)&bt1[h];
    const float* pbS = &bS.x;
    const float* pbT = &bT.x;
    short4 ss, st;
    short* ps = &ss.x;
    short* pt = &st.x;
#pragma unroll
    for (int j = 0; j < 4; ++j) {
      ps[j] = f2bf(1.f / (1.f + __expf(-(acc[0][ht][j] + pbS[j]))));
      pt[j] = f2bf(1.f / (1.f + __expf(-(acc[1][ht][j] + pbT[j]))));
    }
    *(short4*)&rowS[h] = ss;
    *(short4*)&rowT[h] = st;
  }
}

// ---------------------------------------------------------------------------
// Kernel 3 (v4): pipelined MFMA memory-enhance.
//   Grid (642, 2); 256 thr / 4 waves; 64 rows/block, wave owns 16 rows +
//   all 512 f. 8 staged tiles (M0,T0,..,M3,T3) of 32 KB, double-buffered,
//   copied linearly via global_load_lds from the pre-swizzled image;
//   fragment reads apply slot ^= row&7 (bank-floor). No max subtraction
//   (scores bounded, softmax shift-invariant) -> single fused pass:
//   scores -> exp -> PV, accO accumulated across tiles, normalize at end.
// ---------------------------------------------------------------------------
__global__ __launch_bounds__(256) void memenh_mfma(
    const short* __restrict__ stgS, const short* __restrict__ stgT,
    short* __restrict__ r2s, short* __restrict__ r2t) {
  int br = blockIdx.y;
  const short* stg = br ? stgT : stgS;
  short* r2 = br ? r2t : r2s;

  __shared__ __align__(16) short buf[2][16384];  // 64 KB
  int tid = threadIdx.x;
  int l = tid & 63, lr = l & 15, lg = l >> 4;
  int wbase = tid & 192;  // wave index * 64
  int n = blockIdx.x * 64 + (tid >> 6) * 16 + lr;

  // B-frags: this wave's 16 R rows
  bf16x8 brag[4];
  {
    const short* rb = r2 + (size_t)n * 256 + 128;
#pragma unroll
    for (int k = 0; k < 4; ++k) brag[k] = ldfrag(rb + k * 32 + lg * 4);
  }

#define STAGE(t, bsel)                                                        \
  {                                                                           \
    const short* g = stg + (size_t)(t)*16384;                                 \
    _Pragma("unroll") for (int i = 0; i < 8; ++i) {                           \
      gload_lds16(g + (size_t)(i * 256 + tid) * 8,                            \
                  &buf[bsel][(i * 256 + wbase) * 8]);                         \
    }                                                                         \
  }

  STAGE(0, 0);
  __syncthreads();

  f32x4 accO[8];
#pragma unroll
  for (int i = 0; i < 8; ++i) accO[i] = (f32x4){0.f, 0.f, 0.f, 0.f};
  bf16x8 pb[4];
  float ssum = 0.f;
  int cur = 0;

#pragma unroll
  for (int t = 0; t < 8; ++t) {
    if (t < 7) STAGE(t + 1, cur ^ 1);
    const short* tb = &buf[cur][0];
    if ((t & 1) == 0) {
      // score tile: S^T = mem_tile . R^T, then exp (+sum) and pack P-frags
      f32x4 sc[8];
#pragma unroll
      for (int ft16 = 0; ft16 < 8; ++ft16) {
        f32x4 a = {0.f, 0.f, 0.f, 0.f};
#pragma unroll
        for (int k = 0; k < 4; ++k) {
          int row = ft16 * 16 + lr;
          int slot = (4 * k + lg) ^ (row & 7);
          bf16x8 af = *(const bf16x8*)&tb[row * 128 + slot * 8];
          a = __builtin_amdgcn_mfma_f32_16x16x32_bf16(af, brag[k], a, 0, 0, 0);
        }
        sc[ft16] = a;
      }
#pragma unroll
      for (int i = 0; i < 8; ++i) {
        f32x4 v = sc[i];
#pragma unroll
        for (int j = 0; j < 4; ++j) {
          float e = __expf(v[j]);
          v[j] = e;
          ssum += e;
        }
        sc[i] = v;
      }
#pragma unroll
      for (int t4 = 0; t4 < 4; ++t4) {
        f32x4 e0 = sc[2 * t4], e1 = sc[2 * t4 + 1];
        bf16x8 f;
        f[0] = f2bf(e0[0]); f[1] = f2bf(e0[1]);
        f[2] = f2bf(e0[2]); f[3] = f2bf(e0[3]);
        f[4] = f2bf(e1[0]); f[5] = f2bf(e1[1]);
        f[6] = f2bf(e1[2]); f[7] = f2bf(e1[3]);
        pb[t4] = f;
      }
    } else {
      // PV tile: accO += memT_tile . P^T
#pragma unroll
      for (int dt = 0; dt < 8; ++dt) {
#pragma unroll
        for (int k = 0; k < 4; ++k) {
          int row = dt * 16 + lr;
          int slot = (4 * k + lg) ^ (row & 7);
          bf16x8 af = *(const bf16x8*)&tb[row * 128 + slot * 8];
          accO[dt] =
              __builtin_amdgcn_mfma_f32_16x16x32_bf16(af, pb[k], accO[dt], 0, 0, 0);
        }
      }
    }
    __syncthreads();
    cur ^= 1;
  }
#undef STAGE

  // normalize + store O as bf16 to r2[n][0..127]
  ssum += __shfl_xor(ssum, 16);
  ssum += __shfl_xor(ssum, 32);
  float inv = 1.f / ssum;
  short* rowO = r2 + (size_t)n * 256;
#pragma unroll
  for (int dt = 0; dt < 8; ++dt) {
    short4 o;
    o.x = f2bf(accO[dt][0] * inv);
    o.y = f2bf(accO[dt][1] * inv);
    o.z = f2bf(accO[dt][2] * inv);
    o.w = f2bf(accO[dt][3] * inv);
    *(short4*)&rowO[dt * 16 + lg * 4] = o;
  }
}

// ---------------------------------------------------------------------------
// Kernel 4: MFMA GEMM2 (bf16, K=512 concat) + bias + transposed store.
//   (unchanged)
// ---------------------------------------------------------------------------
__global__ __launch_bounds__(512) void gemm2_mfma(
    const short* __restrict__ r2s, const short* __restrict__ r2t,
    const short* __restrict__ W2b,  // [336][512] bf16
    const float* __restrict__ b2,   // [336]
    float* __restrict__ out) {
  __shared__ __align__(16) short w2lds[2][112 * 40];  // 17.9 KB
  int tid = threadIdx.x;
  int w = tid >> 6, l = tid & 63, lr = l & 15, lg = l >> 4;
  int p0 = blockIdx.y * 112;
  int n = blockIdx.x * 128 + w * 16 + lr;
  int b = n / CC, c = n - b * CC;
  const short* rs = r2s + (size_t)n * 256;
  const short* rt = r2t + (size_t)n * 256;

  bool dostage = tid < 448;
  int row = tid >> 2, q = tid & 3;
  const short* gW = W2b + (size_t)(p0 + row) * 512 + q * 4;
  int doff = row * 40 + q * 8;

  f32x4 acc[7];
#pragma unroll
  for (int i = 0; i < 7; ++i) acc[i] = (f32x4){0.f, 0.f, 0.f, 0.f};

  if (dostage) *(int4*)&w2lds[0][doff] = stage_chunk(gW);
  __syncthreads();

  int cur = 0;
  for (int step = 0; step < 16; ++step) {
    int k0 = step * 32;
    const short* rrow = ((k0 < 256) ? rs : rt) + (k0 & 255);
    bf16x8 bfr = ldfrag(rrow + lg * 4);
    int4 nxt = {0, 0, 0, 0};
    if (step < 15 && dostage) nxt = stage_chunk(gW + (step + 1) * 32);
    const short* tw = &w2lds[cur][0];
#pragma unroll
    for (int pt = 0; pt < 7; ++pt) {
      bf16x8 a = ldsfragP(tw, pt * 16 + lr, lg);
      acc[pt] = __builtin_amdgcn_mfma_f32_16x16x32_bf16(a, bfr, acc[pt], 0, 0, 0);
    }
    if (step < 15 && dostage) *(int4*)&w2lds[cur ^ 1][doff] = nxt;
    __syncthreads();
    cur ^= 1;
  }

  size_t obase = (size_t)b * ((size_t)PP * CC) + c;
#pragma unroll
  for (int pt = 0; pt < 7; ++pt) {
    int p = p0 + pt * 16 + lg * 4;
    float4 bias = *(const float4*)&b2[p];
    const float* pb = &bias.x;
#pragma unroll
    for (int j = 0; j < 4; ++j) {
      out[obase + (size_t)(p + j) * CC] = acc[pt][j] + pb[j];
    }
  }
}

// ---------------------------------------------------------------------------
extern "C" void kernel_launch(void* const* d_in, const int* in_sizes, int n_in,
                              void* d_out, int out_size, void* d_ws, size_t ws_size,
                              hipStream_t stream) {
  const float* x    = (const float*)d_in[0];
  const float* Ws1  = (const float*)d_in[1];
  const float* bs1  = (const float*)d_in[2];
  const float* Ws2  = (const float*)d_in[3];
  const float* bs2  = (const float*)d_in[4];
  const float* Wt1  = (const float*)d_in[5];
  const float* bt1  = (const float*)d_in[6];
  const float* Wt2  = (const float*)d_in[7];
  const float* bt2  = (const float*)d_in[8];
  const float* memS = (const float*)d_in[9];
  const float* memT = (const float*)d_in[10];
  float* out = (float*)d_out;

  const size_t N = (size_t)BB * CC;          // 41088
  short* r2s  = (short*)d_ws;                // [N][256] bf16: [O | R]
  short* r2t  = r2s + N * 256;
  short* WsTb = r2t + N * 256;               // [H][LPAD] bf16
  short* WtTb = WsTb + (size_t)HH * LPAD;
  short* stgS = WtTb + (size_t)HH * LPAD;    // staged image: 16384 chunks x 8
  short* stgT = stgS + (size_t)16384 * 8;
  short* W2b  = stgT + (size_t)16384 * 8;    // [336][512] bf16
  float* b2   = (float*)(W2b + (size_t)PP * 512);
  // total ~= 43 MB

  // 1. precompute weights / staged conversions
  weff_kernel<<<(HH * LPAD) / 256, 256, 0, stream>>>(Ws1, Wt1, WsTb, WtTb);
  memstage_kernel<<<128, 256, 0, stream>>>(memS, memT, stgS, stgT);
  w2cvt_kernel<<<(PP * 512) / 256, 256, 0, stream>>>(Ws2, Wt2, bs2, bt2, W2b, b2);

  // 2. MFMA GEMM1 + sigmoid (both branches), grid 642
  gemm1_mfma<<<642, 256, 0, stream>>>(x, WsTb, WtTb, bs1, bt1, r2s, r2t);

  // 3. pipelined MFMA memory enhance, both branches in one dispatch
  dim3 g3(642, 2);
  memenh_mfma<<<g3, 256, 0, stream>>>(stgS, stgT, r2s, r2t);

  // 4. MFMA GEMM2 + bias + transposed store
  dim3 g2(321, 3);
  gemm2_mfma<<<g2, 512, 0, stream>>>(r2s, r2t, W2b, b2, out);
}